// Round 16
// baseline (935.750 us; speedup 1.0000x reference)
//
#include <hip/hip_runtime.h>
#include <cstdint>
#include <cstddef>

// ---------------------------------------------------------------------------
// VQ-VAE forward, MFMA split-bf16 (gfx950), round 16.
//  = round 15 with enc_conv widened to 512-thread blocks (8 waves) using a
//    2-way K-split: waves (wm,wn,kh); kh halves the ct loop; K-halves summed
//    via a 16KB LDS buffer aliasing the dead B region (LDS unchanged ->
//    still 2 blocks/CU, now 16 waves/CU = 4 waves/SIMD latency coverage).
//    Accumulator regrouping only (ulp-level, same class as quad-acc).
// ---------------------------------------------------------------------------

#define DEVI __device__ __forceinline__

typedef short  short8 __attribute__((ext_vector_type(8)));
typedef __bf16 bf16x8 __attribute__((ext_vector_type(8)));
typedef float  f32x16 __attribute__((ext_vector_type(16)));

DEVI f32x16 MFMA(bf16x8 a, bf16x8 b, f32x16 c){
  return __builtin_amdgcn_mfma_f32_32x32x16_bf16(a, b, c, 0, 0, 0);
}

DEVI ushort f2bf(float f){
  unsigned u = __float_as_uint(f);
  unsigned r = (u + 0x7FFFu + ((u >> 16) & 1u)) >> 16;
  return (ushort)r;
}
DEVI float bf2f(ushort h){ return __uint_as_float(((unsigned)h) << 16); }

union U8 { short8 s; bf16x8 b; };
DEVI bf16x8 ldg8u(const ushort* p){
  U8 u; u.s = *(const short8*)p; return u.b;
}

DEVI float wred64(float v){
  #pragma unroll
  for (int off=32; off>0; off>>=1) v += __shfl_down(v, off, 64);
  return v;
}

// ---- output layout (float32 elements) ----
#define O_RECON     0
#define O_RLOSS     2097152
#define O_CODES     2097153
#define O_ZQ        2105345
#define O_COMMIT    2629633
#define O_CB        2629634
#define O_DIV       2629635
#define O_UE        2629636
#define O_PERP      2629637
#define O_ACT       2629638

// ---- workspace layout (bytes) ----
#define WS_R1       0ull
#define A3H_OFF     0ull
#define A3M_OFF     8912896ull
#define A3L_OFF     17825792ull
#define PP_OFF      33554432ull
#define MT_OFF      37748736ull
#define PARTA_OFF   41943040ull
#define A2H_OFF     134217728ull
#define A2M_OFF     151519232ull
#define A2L_OFF     168820736ull
#define EH_OFF      134217728ull
#define EM_OFF      135266304ull
#define EL_OFF      136314880ull
#define FH_OFF      137363456ull
#define FM_OFF      138412032ull
#define FL_OFF      139460608ull
#define D2H_OFF     134217728ull
#define D2L_OFF     151519232ull
#define D1H_OFF     168820736ull
#define D1L_OFF     177733632ull
#define WS_FLAT     186646528ull
#define WS_ZQP      188743680ull
#define WS_WT       191102976ull
#define WT_E2       (WS_WT)
#define WT_E3       (WT_E2 + 393216ull)
#define WT_E4       (WT_E3 + 786432ull)
#define WT_D1       (WT_E4 + 786432ull)
#define WT_D2       (WT_D1 + 524288ull)
#define WT_D3       (WT_D2 + 524288ull)
#define WS_W4       (WT_D3 + 262144ull)
#define WS_STATS    (WS_W4 + 4096ull)
#define ST_RMP      (WS_STATS)
#define ST_CNT      (ST_RMP + 65536ull)
#define ST_AVGS     (ST_CNT + 32768ull)
#define ST_ROWZI    (ST_AVGS + 32768ull)
#define ST_CODESQ   (ST_ROWZI + 32768ull)
#define ST_LOSS     (ST_CODESQ + 32768ull)
#define ST_ROWM     (ST_LOSS + 32768ull)

// ---------------------------------------------------------------------------
DEVI void wsplit_body(int i, const float* src, ushort* dh, ushort* dm,
                      ushort* dl, int OC, int CIN, int isT, int three)
{
  if (i >= 16*OC*CIN) return;
  int cin = i % CIN; int t = i / CIN; int oc = t % OC; int tap = t / OC;
  int st;
  if (isT){
    int pq = tap>>2, ab = tap&3;
    int p = pq>>1, q = pq&1, a = ab>>1, b = ab&1;
    st = (p + 2*a)*4 + (q + 2*b);
  } else st = tap;
  float v = src[((size_t)oc*CIN + cin)*16 + st];
  ushort h = f2bf(v); float r = v - bf2f(h);
  if (three){
    ushort m = f2bf(r); float r2 = r - bf2f(m);
    dm[i] = m; dl[i] = f2bf(r2);
  } else {
    dl[i] = f2bf(r);
  }
  dh[i] = h;
}

DEVI void zpad_body(int i, unsigned* b0, unsigned* b1, unsigned* b2,
                    int rows, int Wp, int cwords)
{
  int total = rows*2*cwords;
  if (i >= total) return;
  int pos = i / cwords, cw = i % cwords;
  int row = pos >> 1, side = pos & 1;
  size_t w = ((size_t)row*Wp + (side ? (Wp-1) : 0))*cwords + cw;
  b0[w] = 0u;
  if (b1) b1[w] = 0u;
  if (b2) b2[w] = 0u;
}

// one launch: init + all weight splits + w4prep + A2/zqP pad zeroing
__global__ __launch_bounds__(256) void k_prep(
    const float* __restrict__ ew2, const float* __restrict__ ew3,
    const float* __restrict__ ew4, const float* __restrict__ dw1,
    const float* __restrict__ dw2, const float* __restrict__ dw3,
    const float* __restrict__ dw4,
    ushort* wE2h, ushort* wE2m, ushort* wE2l,
    ushort* wE3h, ushort* wE3m, ushort* wE3l,
    ushort* wE4h, ushort* wE4m, ushort* wE4l,
    ushort* wD1h, ushort* wD1l, ushort* wD2h, ushort* wD2l,
    ushort* wD3h, ushort* wD3l, float* w4,
    unsigned* A2h, unsigned* A2m, unsigned* A2l,
    unsigned* zqPh, unsigned* zqPl,
    unsigned int* cnt, unsigned long long* rmp, float* loss)
{
  int b = blockIdx.x, tid = threadIdx.x;
  if (b < 32){
    int i = b*256 + tid;
    if (i < 8192){ cnt[i]=0u; rmp[i]=0xFFFFFFFFFFFFFFFFull; }
    if (i < 8) loss[i]=0.f;
  } else if (b < 288){
    wsplit_body((b-32)*256 + tid, ew2, wE2h, wE2m, wE2l, 64, 64, 0, 1);
  } else if (b < 800){
    wsplit_body((b-288)*256 + tid, ew3, wE3h, wE3m, wE3l, 128, 64, 0, 1);
  } else if (b < 1312){
    wsplit_body((b-800)*256 + tid, ew4, wE4h, wE4m, wE4l, 64, 128, 0, 1);
  } else if (b < 1824){
    wsplit_body((b-1312)*256 + tid, dw1, wD1h, nullptr, wD1l, 128, 64, 1, 0);
  } else if (b < 2336){
    wsplit_body((b-1824)*256 + tid, dw2, wD2h, nullptr, wD2l, 64, 128, 1, 0);
  } else if (b < 2592){
    wsplit_body((b-2336)*256 + tid, dw3, wD3h, nullptr, wD3l, 64, 64, 1, 0);
  } else if (b < 2596){
    int i = (b-2592)*256 + tid;
    if (i < 1024){
      int c = i & 63; int t16 = i >> 6;
      int pq = t16 >> 2, ab = t16 & 3;
      int p = pq>>1, q = pq&1, a = ab>>1, bb = ab&1;
      w4[i] = dw4[(size_t)c*16 + (p+2*a)*4 + (q+2*bb)];
    }
  } else if (b < 3108){
    zpad_body((b-2596)*256 + tid, A2h, A2m, A2l, 32*64, 66, 32);
  } else {
    zpad_body((b-3108)*256 + tid, zqPh, zqPl, nullptr, 32*16, 18, 32);
  }
}

__global__ __launch_bounds__(256) void k_zpadA3(unsigned* b0, unsigned* b1,
                                                unsigned* b2)
{
  zpad_body(blockIdx.x*256 + threadIdx.x, b0, b1, b2, 32*32, 34, 64);
}

// merged: embed split (blocks 0..2047) + codesq (blocks 2048..4095)
__global__ __launch_bounds__(256) void k_eprep(
    const float* __restrict__ embed,
    ushort* __restrict__ dh, ushort* __restrict__ dm, ushort* __restrict__ dl,
    float* __restrict__ codesq)
{
  int b = blockIdx.x;
  if (b < 2048){
    int i = b*256 + threadIdx.x;
    float v = embed[i];
    ushort h = f2bf(v); float r1 = v - bf2f(h);
    ushort m = f2bf(r1); float r2 = r1 - bf2f(m);
    dh[i] = h; dm[i] = m; dl[i] = f2bf(r2);
  } else {
    int j = (b-2048)*4 + (threadIdx.x>>6);
    int c = threadIdx.x & 63;
    float e = embed[(size_t)j*64 + c];
    float s = wred64(e*e);
    if (c==0) codesq[j] = s;
  }
}

// ---------------------------------------------------------------------------
// conv1: 1->64ch, k4 s2 p1, direct fp32, writes NHWC fp32 [32][128][128][64]
// ---------------------------------------------------------------------------
__global__ __launch_bounds__(256) void enc_conv1(
    const float* __restrict__ x, const float* __restrict__ w,
    const float* __restrict__ cb_, const float* __restrict__ bns,
    const float* __restrict__ bnb, float* __restrict__ out)
{
  __shared__ __align__(16) float sIn[34][36];
  __shared__ __align__(16) float sW[64][16];
  int b = blockIdx.x;
  int t = b & 63, n = b >> 6;
  int ty = t >> 3, tx = t & 7;
  int oy0 = ty*16, ox0 = tx*16;
  int iy0 = 2*oy0 - 1, ix0 = 2*ox0 - 1;
  int tid = threadIdx.x;
  int spg = tid & 31, og = tid >> 5;
  int sy = spg >> 1, x0 = (spg & 1)*8;

  if (tid < 64){
    const float* wp = w + tid*16;
    *(float4*)&sW[tid][0]  = *(const float4*)(wp);
    *(float4*)&sW[tid][4]  = *(const float4*)(wp+4);
    *(float4*)&sW[tid][8]  = *(const float4*)(wp+8);
    *(float4*)&sW[tid][12] = *(const float4*)(wp+12);
  }
  for (int e = tid; e < 34*34; e += 256){
    int rr = e/34, cc = e%34;
    int iy = iy0+rr, ix = ix0+cc;
    float v = 0.f;
    if ((unsigned)iy < 256u && (unsigned)ix < 256u)
      v = x[(size_t)n*65536 + iy*256 + ix];
    sIn[rr][cc] = v;
  }
  __syncthreads();

  float acc[8][8];
  #pragma unroll
  for (int j=0;j<8;j++)
    #pragma unroll
    for (int xi=0;xi<8;xi++) acc[j][xi]=0.f;

  #pragma unroll
  for (int ky=0; ky<4; ky++){
    int riy = 2*sy + ky;
    float seg[20];
    #pragma unroll
    for (int i=0;i<5;i++){
      float4 v = *(const float4*)&sIn[riy][2*x0 + 4*i];
      seg[4*i+0]=v.x; seg[4*i+1]=v.y; seg[4*i+2]=v.z; seg[4*i+3]=v.w;
    }
    #pragma unroll
    for (int j=0;j<8;j++){
      float4 w4v = *(const float4*)&sW[og*8+j][ky*4];
      #pragma unroll
      for (int xi=0; xi<8; xi++){
        acc[j][xi] = fmaf(seg[2*xi+0], w4v.x,
                     fmaf(seg[2*xi+1], w4v.y,
                     fmaf(seg[2*xi+2], w4v.z,
                     fmaf(seg[2*xi+3], w4v.w, acc[j][xi]))));
      }
    }
  }

  float sc[8], sh[8];
  #pragma unroll
  for (int j=0;j<8;j++){
    int oc = og*8+j;
    sc[j] = bns[oc];
    sh[j] = fmaf(cb_[oc], sc[j], bnb[oc]);
  }
  int oy = oy0 + sy;
  #pragma unroll
  for (int xi=0; xi<8; xi++){
    int oxg = ox0 + x0 + xi;
    float* op = out + (((size_t)n*128 + oy)*128 + oxg)*64 + og*8;
    float4 q0, q1;
    q0.x = fmaxf(fmaf(acc[0][xi], sc[0], sh[0]), 0.f);
    q0.y = fmaxf(fmaf(acc[1][xi], sc[1], sh[1]), 0.f);
    q0.z = fmaxf(fmaf(acc[2][xi], sc[2], sh[2]), 0.f);
    q0.w = fmaxf(fmaf(acc[3][xi], sc[3], sh[3]), 0.f);
    q1.x = fmaxf(fmaf(acc[4][xi], sc[4], sh[4]), 0.f);
    q1.y = fmaxf(fmaf(acc[5][xi], sc[5], sh[5]), 0.f);
    q1.z = fmaxf(fmaf(acc[6][xi], sc[6], sh[6]), 0.f);
    q1.w = fmaxf(fmaf(acc[7][xi], sc[7], sh[7]), 0.f);
    *(float4*)op     = q0;
    *(float4*)(op+4) = q1;
  }
}

// ---------------------------------------------------------------------------
// Encoder conv k4 s2 p1 tap-GEMM, 6-term MFMA, quad-acc, 512 threads (8 waves,
// 2-way K-split). A+B staged in LDS, B reg-prefetched; K-halves summed via
// LDS buffer aliasing B. DIRECT epilogue stores (oc in lanes).
// ---------------------------------------------------------------------------
template<int CIN, int OC, int OUTW, int OUTH, int INW, int INH, bool XPAD,
         int INMODE, int OUTMODE>
__global__ __launch_bounds__(512) void enc_conv(
    const float* __restrict__ in,
    const ushort* __restrict__ aH, const ushort* __restrict__ aM,
    const ushort* __restrict__ aL,
    const ushort* __restrict__ wtH, const ushort* __restrict__ wtM,
    const ushort* __restrict__ wtL,
    const float* __restrict__ cb_, const float* __restrict__ bns,
    const float* __restrict__ bnb,
    float* __restrict__ outF,
    ushort* __restrict__ oH, ushort* __restrict__ oM, ushort* __restrict__ oL,
    int nOcg)
{
  constexpr int INWP  = (INMODE==1) ? (INW+2) : (XPAD ? (INW+2) : INW);
  constexpr int WP    = INW + 2;
  constexpr int NROWS = 64 / OUTW;
  constexpr int AELEM = NROWS * WP * CIN;
  constexpr int BCIN  = (CIN > 64) ? 64 : CIN;     // 64 for all instantiations
  constexpr int BELEM = 64 * BCIN;                 // 4096
  constexpr int NCH   = CIN / BCIN;
  constexpr int NSTG  = 16 * NCH;
  constexpr int NT    = 512;
  constexpr int SCRSZ = (3*BELEM*2 > 4*64*16*4) ? 3*BELEM*2 : 4*64*16*4; // 24576

  __shared__ __align__(16) ushort sAh[AELEM], sAm[AELEM], sAl[AELEM];
  __shared__ __align__(16) char sScr[SCRSZ];
  ushort* sBh = (ushort*)sScr;
  ushort* sBm = sBh + BELEM;
  ushort* sBl = sBm + BELEM;
  float*  sRed = (float*)sScr;     // aliases B; used only after last MFMA

  int b = blockIdx.x;
  int ocg = b % nOcg; b /= nOcg;
  int yb  = b % (OUTH/NROWS); b /= (OUTH/NROWS);
  int n = b;
  int oy0 = yb * NROWS, oc0 = ocg * 64;

  int tid = threadIdx.x;
  int l = tid & 63, wave = tid >> 6;      // 8 waves
  int kh = wave & 1;                      // K-half
  int wq = wave >> 1;                     // output sub-tile 0..3
  int wm = wq >> 1, wn = wq & 1;
  int r = l & 31, kp = l >> 5;
  int idx = wm*32 + r;
  int oy_off = idx / OUTW, ox = idx % OUTW;

  // B prefetch: exactly one 8-elem item per thread (BELEM/8 == NT)
  int pfoc = tid / (BCIN/8);
  int pfc8 = (tid % (BCIN/8)) * 8;
  short8 pf0, pf1, pf2;
  {
    size_t off = ((size_t)oc0 + pfoc)*CIN + pfc8;
    pf0 = *(const short8*)(wtH + off);
    pf1 = *(const short8*)(wtM + off);
    pf2 = *(const short8*)(wtL + off);
  }

  f32x16 acc0, acc1, acc2, acc3;
  #pragma unroll
  for (int i=0;i<16;i++){ acc0[i]=0.f; acc1[i]=0.f; acc2[i]=0.f; acc3[i]=0.f; }

  const size_t nbase = (size_t)n * INH * INWP * CIN;
  int sidx = 0;

  for (int ky = 0; ky < 4; ky++){
    __syncthreads();
    for (int c = tid; c < AELEM/8; c += NT){
      int j  = c / (WP*CIN/8);
      int rm = c % (WP*CIN/8);
      int lx = rm / (CIN/8);
      int c8 = (rm % (CIN/8)) * 8;
      int iy = 2*(oy0 + j) - 1 + ky;
      bool ok = (unsigned)iy < (unsigned)INH;
      unsigned off = (unsigned)(((j*WP + lx)*CIN + c8)*2) ^ ((((unsigned)lx>>1)&15u)<<4);
      if constexpr (INMODE == 0){
        int gx = XPAD ? lx : (lx - 1);
        if (!XPAD) ok = ok && ((unsigned)gx < (unsigned)INW);
        float4 v0 = {0,0,0,0}, v1 = {0,0,0,0};
        if (ok){
          const float* s = in + nbase + ((size_t)iy*INWP + gx)*CIN + c8;
          v0 = *(const float4*)s; v1 = *(const float4*)(s+4);
        }
        float vv[8] = {v0.x,v0.y,v0.z,v0.w,v1.x,v1.y,v1.z,v1.w};
        short8 hh, mm, ll;
        #pragma unroll
        for (int e=0;e<8;e++){
          ushort h = f2bf(vv[e]); float r1 = vv[e] - bf2f(h);
          ushort m = f2bf(r1);    float r2 = r1 - bf2f(m);
          hh[e] = (short)h; mm[e] = (short)m; ll[e] = (short)f2bf(r2);
        }
        *(short8*)((char*)sAh + off) = hh;
        *(short8*)((char*)sAm + off) = mm;
        *(short8*)((char*)sAl + off) = ll;
      } else {
        short8 vh = {0,0,0,0,0,0,0,0}, vm = vh, vl = vh;
        if (ok){
          size_t s = nbase + ((size_t)iy*INWP + lx)*CIN + c8;
          vh = *(const short8*)(aH + s);
          vm = *(const short8*)(aM + s);
          vl = *(const short8*)(aL + s);
        }
        *(short8*)((char*)sAh + off) = vh;
        *(short8*)((char*)sAm + off) = vm;
        *(short8*)((char*)sAl + off) = vl;
      }
    }
    for (int kx = 0; kx < 4; kx++){
      for (int chi = 0; chi < NCH; chi++){
        int ch = chi * BCIN;
        __syncthreads();
        {
          unsigned off = (unsigned)((pfoc*BCIN + pfc8)*2)
                         ^ (((unsigned)pfoc&15u)<<4);
          *(short8*)((char*)sBh + off) = pf0;
          *(short8*)((char*)sBm + off) = pf1;
          *(short8*)((char*)sBl + off) = pf2;
        }
        __syncthreads();
        if (sidx + 1 < NSTG){
          int ns = sidx + 1;
          int ntap = ns / NCH, nchi = ns % NCH;
          size_t off = ((size_t)ntap*OC + oc0 + pfoc)*CIN + nchi*BCIN + pfc8;
          pf0 = *(const short8*)(wtH + off);
          pf1 = *(const short8*)(wtM + off);
          pf2 = *(const short8*)(wtL + off);
        }
        sidx++;
        int lx = 2*ox + kx;
        unsigned asw  = ((((unsigned)lx>>1)&15u)<<4);
        unsigned alin = (unsigned)(((oy_off*WP + lx)*CIN)*2);
        int ocl = wn*32 + r;
        unsigned bsw  = (((unsigned)ocl&15u)<<4);
        unsigned blin = (unsigned)((ocl*BCIN)*2);
        #pragma unroll
        for (int ct2 = 0; ct2 < 2; ct2++){
          int ct = kh*2 + ct2;
          unsigned kbA = (unsigned)((ch + ct*16 + kp*8)*2);
          unsigned kbB = (unsigned)((ct*16 + kp*8)*2);
          unsigned ao = (alin + kbA) ^ asw;
          unsigned bo = (blin + kbB) ^ bsw;
          bf16x8 ah = *(const bf16x8*)((char*)sAh + ao);
          bf16x8 am = *(const bf16x8*)((char*)sAm + ao);
          bf16x8 al = *(const bf16x8*)((char*)sAl + ao);
          bf16x8 bh = *(const bf16x8*)((char*)sBh + bo);
          bf16x8 bm = *(const bf16x8*)((char*)sBm + bo);
          bf16x8 bl = *(const bf16x8*)((char*)sBl + bo);
          acc0 = MFMA(ah, bh, acc0);
          acc1 = MFMA(ah, bm, acc1);
          acc2 = MFMA(am, bh, acc2);
          acc3 = MFMA(ah, bl, acc3);
          acc0 = MFMA(am, bm, acc0);
          acc1 = MFMA(al, bh, acc1);
        }
      }
    }
  }
  // ---- K-half reduce via LDS (aliases dead B) + direct epilogue ----
  __syncthreads();
  if (kh == 1){
    float* dst = sRed + ((size_t)(wq*64 + l)*16);
    #pragma unroll
    for (int q = 0; q < 16; q++)
      dst[q] = (acc0[q] + acc1[q]) + (acc2[q] + acc3[q]);
  }
  __syncthreads();
  if (kh == 0){
    const float* srcp = sRed + ((size_t)(wq*64 + l)*16);
    int oce = oc0 + wn*32 + r;
    if constexpr (OUTMODE == 1){
      float cbv = cb_[oce];
      #pragma unroll
      for (int q = 0; q < 16; q++){
        int rowt = (q&3) + 8*(q>>2) + 4*kp;
        int m = wm*32 + rowt;
        int oyg = oy0 + m / OUTW;
        int oxg = m % OUTW;
        size_t row = (size_t)n*256 + oyg*16 + oxg;
        float v = ((acc0[q] + acc1[q]) + (acc2[q] + acc3[q])) + srcp[q] + cbv;
        outF[row*64 + oce] = v;
        ushort h = f2bf(v); float r1 = v - bf2f(h);
        ushort mm = f2bf(r1); float r2 = r1 - bf2f(mm);
        oH[row*64 + oce] = h;
        oM[row*64 + oce] = mm;
        oL[row*64 + oce] = f2bf(r2);
      }
    } else {
      float s1 = bns[oce];
      float s2 = fmaf(cb_[oce], s1, bnb[oce]);
      #pragma unroll
      for (int q = 0; q < 16; q++){
        int rowt = (q&3) + 8*(q>>2) + 4*kp;
        int m = wm*32 + rowt;
        int oyg = oy0 + m / OUTW;
        int oxg = m % OUTW;
        size_t pbase = (((size_t)n*OUTH + oyg)*(OUTW+2) + oxg + 1)*OC + oce;
        float acc = ((acc0[q] + acc1[q]) + (acc2[q] + acc3[q])) + srcp[q];
        float v = fmaxf(fmaf(acc, s1, s2), 0.f);
        ushort h = f2bf(v); float r1 = v - bf2f(h);
        ushort mm = f2bf(r1); float r2 = r1 - bf2f(mm);
        oH[pbase] = h;
        oM[pbase] = mm;
        oL[pbase] = f2bf(r2);
      }
    }
  }
}

DEVI float rmp_minval(unsigned long long v){
  unsigned skey = (unsigned)(v >> 32);
  unsigned u = (skey & 0x80000000u) ? (skey ^ 0x80000000u) : ~skey;
  return __uint_as_float(u);
}

// ---------------------------------------------------------------------------
// VQ pass 1, swapped operands (codes in rows), in-register argmin.
// ---------------------------------------------------------------------------
__global__ __launch_bounds__(256) void vq_min(
    const ushort* __restrict__ fH, const ushort* __restrict__ fM,
    const ushort* __restrict__ fL,
    const ushort* __restrict__ eH, const ushort* __restrict__ eM,
    const ushort* __restrict__ eL,
    const float* __restrict__ codesq,
    unsigned long long* __restrict__ rmp,
    float* __restrict__ Pp, float* __restrict__ Mt)
{
  __shared__ __align__(16) ushort sAh[128*64], sAm[128*64], sAl[128*64];
  int cblk = blockIdx.x & 63, fblk = blockIdx.x >> 6;
  int code0 = cblk*128, f0 = fblk*128;
  int tid = threadIdx.x, l = tid&63, wave = tid>>6;
  int wm = wave>>1, wn = wave&1, r = l&31, kp = l>>5;

  for (int c = tid; c < 1024; c += 256){
    int rr = c >> 3, c8 = (c & 7)*8;
    size_t s = (size_t)(code0+rr)*64 + c8;
    unsigned off = (unsigned)((rr*64 + c8)*2) ^ (((unsigned)rr&15u)<<4);
    *(short8*)((char*)sAh + off) = *(const short8*)(eH + s);
    *(short8*)((char*)sAm + off) = *(const short8*)(eM + s);
    *(short8*)((char*)sAl + off) = *(const short8*)(eL + s);
  }
  __syncthreads();

  f32x16 acc[2][2];
  #pragma unroll
  for (int mt=0;mt<2;mt++)
    #pragma unroll
    for (int nt=0;nt<2;nt++)
      #pragma unroll
      for (int i=0;i<16;i++) acc[mt][nt][i]=0.f;

  #pragma unroll
  for (int ks=0; ks<4; ks++){
    unsigned kb = (unsigned)((ks*16 + kp*8)*2);
    int ko = ks*16 + kp*8;
    bf16x8 Ah[2],Am[2],Al[2],Bh[2],Bm[2],Bl[2];
    #pragma unroll
    for (int mt=0;mt<2;mt++){
      int rowi = wm*64 + mt*32 + r;
      unsigned o = ((unsigned)(rowi*128) + kb) ^ (((unsigned)rowi&15u)<<4);
      Ah[mt] = *(const bf16x8*)((char*)sAh + o);
      Am[mt] = *(const bf16x8*)((char*)sAm + o);
      Al[mt] = *(const bf16x8*)((char*)sAl + o);
    }
    #pragma unroll
    for (int nt=0;nt<2;nt++){
      int coli = f0 + wn*64 + nt*32 + r;
      size_t bo = (size_t)coli*64 + ko;
      Bh[nt] = ldg8u(fH + bo);
      Bm[nt] = ldg8u(fM + bo);
      Bl[nt] = ldg8u(fL + bo);
    }
    #pragma unroll
    for (int mt=0;mt<2;mt++)
      #pragma unroll
      for (int nt=0;nt<2;nt++){
        acc[mt][nt] = MFMA(Ah[mt], Bh[nt], acc[mt][nt]);
        acc[mt][nt] = MFMA(Ah[mt], Bm[nt], acc[mt][nt]);
        acc[mt][nt] = MFMA(Am[mt], Bh[nt], acc[mt][nt]);
        acc[mt][nt] = MFMA(Ah[mt], Bl[nt], acc[mt][nt]);
        acc[mt][nt] = MFMA(Am[mt], Bm[nt], acc[mt][nt]);
        acc[mt][nt] = MFMA(Al[mt], Bh[nt], acc[mt][nt]);
      }
  }

  float cqv[2][16];
  #pragma unroll
  for (int mt=0; mt<2; mt++)
    #pragma unroll
    for (int g=0; g<4; g++){
      float4 cv = *(const float4*)(codesq + code0 + wm*64 + mt*32 + 8*g + 4*kp);
      cqv[mt][4*g+0]=cv.x; cqv[mt][4*g+1]=cv.y;
      cqv[mt][4*g+2]=cv.z; cqv[mt][4*g+3]=cv.w;
    }

  #pragma unroll
  for (int nt=0; nt<2; nt++){
    int col = f0 + wn*64 + nt*32 + r;
    unsigned long long kmin = 0xFFFFFFFFFFFFFFFFull;
    #pragma unroll
    for (int mt=0; mt<2; mt++)
      #pragma unroll
      for (int q=0; q<16; q++){
        float d = cqv[mt][q] - 2.f*acc[mt][nt][q];
        int code = code0 + wm*64 + mt*32 + (q&3) + 8*(q>>2) + 4*kp;
        unsigned u = __float_as_uint(d);
        unsigned sgn = (unsigned)((int)u >> 31);
        unsigned skey = u ^ (sgn | 0x80000000u);
        unsigned long long key = (((unsigned long long)skey)<<32) | (unsigned)code;
        if (key < kmin) kmin = key;
      }
    unsigned long long o2 = __shfl_xor(kmin, 32, 64);
    if (o2 < kmin) kmin = o2;
    float mloc = rmp_minval(kmin);
    float p = 0.f;
    #pragma unroll
    for (int mt=0; mt<2; mt++)
      #pragma unroll
      for (int q=0; q<16; q++){
        float d = cqv[mt][q] - 2.f*acc[mt][nt][q];
        p += __expf(mloc - d);
      }
    p += __shfl_xor(p, 32, 64);
    if (kp == 0){
      atomicMin(&rmp[col], kmin);
      size_t pidx = (size_t)col*128 + (size_t)cblk*2 + wm;
      Pp[pidx] = p;
      Mt[pidx] = mloc;
    }
  }
}

// rowz-lite
__global__ __launch_bounds__(256) void k_rowz2(
    const unsigned long long* __restrict__ rmp,
    const float* __restrict__ Pp, const float* __restrict__ Mt,
    float* __restrict__ rowzi, float* __restrict__ rowm)
{
  int row = blockIdx.x*256 + threadIdx.x;
  float mg = rmp_minval(rmp[row]);
  const float* pp = Pp + (size_t)row*128;
  const float* mt = Mt + (size_t)row*128;
  float z = 0.f;
  for (int t = 0; t < 128; t++)
    z = fmaf(__expf(mg - mt[t]), pp[t], z);
  rowzi[row] = 1.f / z;
  rowm[row] = mg;
}

// ---------------------------------------------------------------------------
// VQ pass 2: recompute tiles (original orientation), col partials.
// ---------------------------------------------------------------------------
__global__ __launch_bounds__(256) void vq_avg(
    const ushort* __restrict__ fH, const ushort* __restrict__ fM,
    const ushort* __restrict__ fL,
    const ushort* __restrict__ eH, const ushort* __restrict__ eM,
    const ushort* __restrict__ eL,
    const float* __restrict__ codesq,
    const float* __restrict__ rowm,
    const float* __restrict__ rowzi,
    float* __restrict__ partA)
{
  __shared__ __align__(16) ushort sAh[128*64], sAm[128*64], sAl[128*64];
  __shared__ float colbuf[128];
  int cb = blockIdx.x & 63, rb = blockIdx.x >> 6;
  int row0 = rb*128, c0 = cb*128;
  int tid = threadIdx.x, l = tid&63, wave = tid>>6;
  int wm = wave>>1, wn = wave&1, r = l&31, kp = l>>5;

  if (tid < 128) colbuf[tid] = 0.f;

  for (int c = tid; c < 1024; c += 256){
    int rr = c >> 3, c8 = (c & 7)*8;
    size_t s = (size_t)(row0+rr)*64 + c8;
    unsigned off = (unsigned)((rr*64 + c8)*2) ^ (((unsigned)rr&15u)<<4);
    *(short8*)((char*)sAh + off) = *(const short8*)(fH + s);
    *(short8*)((char*)sAm + off) = *(const short8*)(fM + s);
    *(short8*)((char*)sAl + off) = *(const short8*)(fL + s);
  }
  __syncthreads();

  f32x16 acc[2][2];
  #pragma unroll
  for (int mt=0;mt<2;mt++)
    #pragma unroll
    for (int nt=0;nt<2;nt++)
      #pragma unroll
      for (int i=0;i<16;i++) acc[mt][nt][i]=0.f;

  #pragma unroll
  for (int ks=0; ks<4; ks++){
    unsigned kb = (unsigned)((ks*16 + kp*8)*2);
    int ko = ks*16 + kp*8;
    bf16x8 Ah[2],Am[2],Al[2],Bh[2],Bm[2],Bl[2];
    #pragma unroll
    for (int mt=0;mt<2;mt++){
      int rowi = wm*64 + mt*32 + r;
      unsigned o = ((unsigned)(rowi*128) + kb) ^ (((unsigned)rowi&15u)<<4);
      Ah[mt] = *(const bf16x8*)((char*)sAh + o);
      Am[mt] = *(const bf16x8*)((char*)sAm + o);
      Al[mt] = *(const bf16x8*)((char*)sAl + o);
    }
    #pragma unroll
    for (int nt=0;nt<2;nt++){
      int coli = c0 + wn*64 + nt*32 + r;
      size_t bo = (size_t)coli*64 + ko;
      Bh[nt] = ldg8u(eH + bo);
      Bm[nt] = ldg8u(eM + bo);
      Bl[nt] = ldg8u(eL + bo);
    }
    #pragma unroll
    for (int mt=0;mt<2;mt++)
      #pragma unroll
      for (int nt=0;nt<2;nt++){
        acc[mt][nt] = MFMA(Ah[mt], Bh[nt], acc[mt][nt]);
        acc[mt][nt] = MFMA(Ah[mt], Bm[nt], acc[mt][nt]);
        acc[mt][nt] = MFMA(Am[mt], Bh[nt], acc[mt][nt]);
        acc[mt][nt] = MFMA(Ah[mt], Bl[nt], acc[mt][nt]);
        acc[mt][nt] = MFMA(Am[mt], Bm[nt], acc[mt][nt]);
        acc[mt][nt] = MFMA(Al[mt], Bh[nt], acc[mt][nt]);
      }
  }

  float cq[2];
  cq[0] = codesq[c0 + wn*64 + r];
  cq[1] = codesq[c0 + wn*64 + 32 + r];
  float colacc[2] = {0.f, 0.f};
  #pragma unroll
  for (int mt=0; mt<2; mt++){
    #pragma unroll
    for (int q=0; q<16; q++){
      int rowt = (q&3) + 8*(q>>2) + 4*kp;
      int grow = row0 + wm*64 + mt*32 + rowt;
      float mi = rowm[grow];
      float zi = rowzi[grow];
      #pragma unroll
      for (int nt=0; nt<2; nt++){
        float d = cq[nt] - 2.f*acc[mt][nt][q];
        colacc[nt] = fmaf(__expf(mi - d), zi, colacc[nt]);
      }
    }
  }
  #pragma unroll
  for (int nt=0; nt<2; nt++){
    float o = __shfl_xor(colacc[nt], 32, 64);
    colacc[nt] += o;
    if (l < 32) atomicAdd(&colbuf[wn*64 + nt*32 + r], colacc[nt]);
  }
  __syncthreads();
  if (tid < 128)
    partA[(size_t)rb*8192 + c0 + tid] = colbuf[tid];
}

__global__ __launch_bounds__(256) void k_avgred(const float* __restrict__ partA,
                                                float* __restrict__ avgs)
{
  int j = blockIdx.x*256 + threadIdx.x;
  float s = 0.f;
  for (int rb = 0; rb < 64; rb++)
    s += partA[(size_t)rb*8192 + j];
  avgs[j] = s;
}

// codes, zq, zqP planes, commit SSE, hist. Blocks >= 2048 do D1/D2 pad-zero.
__global__ __launch_bounds__(256) void vq_post(
    const float* __restrict__ flat, const float* __restrict__ embed,
    const unsigned long long* __restrict__ rmp,
    float* __restrict__ out_codes, float* __restrict__ out_zq,
    ushort* __restrict__ zqPh, ushort* __restrict__ zqPl,
    float* __restrict__ loss, unsigned int* __restrict__ cnt,
    unsigned* __restrict__ d1h, unsigned* __restrict__ d1l,
    unsigned* __restrict__ d2h, unsigned* __restrict__ d2l)
{
  int blk = blockIdx.x;
  if (blk >= 2048){
    int zb = blk - 2048;
    if (zb < 512) zpad_body(zb*256 + threadIdx.x, d1h, d1l, nullptr, 32*32, 34, 64);
    else zpad_body((zb-512)*256 + threadIdx.x, d2h, d2l, nullptr, 32*64, 66, 32);
    return;
  }
  int r = blk*4 + (threadIdx.x>>6);
  int c = threadIdx.x & 63;
  unsigned j = (unsigned)(rmp[r] & 0xFFFFFFFFull);
  float e = embed[(size_t)j*64 + c];
  float f = flat[(size_t)r*64 + c];
  int n = r>>8, rem = r&255, gy = rem>>4, gx = rem&15;
  out_zq[(((size_t)n*64 + c)*16 + gy)*16 + gx] = e;
  ushort h = f2bf(e);
  size_t pz = (((size_t)n*16 + gy)*18 + gx + 1)*64 + c;
  zqPh[pz] = h; zqPl[pz] = f2bf(e - bf2f(h));
  float d = f - e;
  float s2 = wred64(d*d);
  if (c==0){
    out_codes[r] = (float)j;
    atomicAdd(cnt + j, 1u);
    atomicAdd(loss + 1, s2);
  }
}

// ---------------------------------------------------------------------------
// PARITY-MERGED decoder convT, 3-term MFMA, TRI-acc, DIRECT epilogue stores.
// ---------------------------------------------------------------------------
template<int CIN, int OC, int SW, int SH, bool OUTPAD, int OMODE, int NPAR>
__global__ __launch_bounds__(256) void dec_convT_m(
    const ushort* __restrict__ inH, const ushort* __restrict__ inL,
    const ushort* __restrict__ wtH, const ushort* __restrict__ wtL,
    const float* __restrict__ db, const float* __restrict__ bns,
    const float* __restrict__ bnb,
    ushort* __restrict__ oH, ushort* __restrict__ oL, int nOcg)
{
  constexpr int TR    = 64 / SW;
  constexpr int NRA   = TR + ((NPAR==4) ? 2 : 1);
  constexpr int WPin  = SW + 2;
  constexpr int AELEM = NRA * WPin * CIN;
  constexpr int OUTH  = 2*SH;
  constexpr int OW    = OUTPAD ? (2*SW+2) : (2*SW);

  __shared__ __align__(16) ushort sAh[AELEM], sAl[AELEM];

  int b = blockIdx.x;
  int p_blk = 0;
  if (NPAR == 2){ p_blk = b & 1; b >>= 1; }
  int ocg = b % nOcg; b /= nOcg;
  int tb = b % (SH/TR); b /= (SH/TR);
  int n = b;
  int t0 = tb * TR, oc0 = ocg * 64;
  const int ROWBASE = (NPAR==4) ? -1 : (p_blk - 1);

  int tid = threadIdx.x, l = tid&63, wave = tid>>6;
  int wm = wave>>1, wn = wave&1;
  int r = l&31, kp = l>>5;
  int idx = wm*32 + r;
  int t_off = idx / SW, s = idx % SW;
  int ocl = oc0 + wn*32 + r;

  float bn_s1 = bns[ocl];
  float bn_s2 = fmaf(db[ocl], bn_s1, bnb[ocl]);

  for (int c = tid; c < AELEM/8; c += 256){
    int j  = c / (WPin*CIN/8);
    int rm = c % (WPin*CIN/8);
    int lx = rm / (CIN/8);
    int c8 = (rm % (CIN/8)) * 8;
    int giy = t0 + ROWBASE + j;
    bool ok = (unsigned)giy < (unsigned)SH;
    short8 vh = {0,0,0,0,0,0,0,0}, vl = {0,0,0,0,0,0,0,0};
    if (ok){
      size_t sidx = (((size_t)n*SH + giy)*WPin + lx)*CIN + c8;
      vh = *(const short8*)(inH + sidx);
      vl = *(const short8*)(inL + sidx);
    }
    unsigned off = (unsigned)(((j*WPin + lx)*CIN + c8)*2) ^ (((unsigned)lx&15u)<<4);
    *(short8*)((char*)sAh + off) = vh;
    *(short8*)((char*)sAl + off) = vl;
  }
  __syncthreads();

  for (int pr = 0; pr < NPAR; pr++){
    int p2 = (NPAR==4) ? (pr>>1) : p_blk;
    int q2 = (NPAR==4) ? (pr&1)  : pr;
    int par = p2*2 + q2;

    f32x16 acc0, acc1, acc2;
    #pragma unroll
    for (int i=0;i<16;i++){ acc0[i]=0.f; acc1[i]=0.f; acc2[i]=0.f; }

    for (int ab = 0; ab < 4; ab++){
      int a = ab>>1, bb = ab&1;
      int rs = t_off + ((NPAR==4) ? (p2 + a) : a);
      int lx = s + q2 + bb;
      unsigned asw  = (((unsigned)lx&15u)<<4);
      unsigned alin = (unsigned)(((rs*WPin + lx)*CIN)*2);
      size_t brow = ((size_t)(par*4 + ab)*OC + ocl)*CIN;
      #pragma unroll
      for (int ct = 0; ct < CIN/16; ct++){
        int ko = ct*16 + kp*8;
        unsigned ao = (alin + (unsigned)(ko*2)) ^ asw;
        bf16x8 ah = *(const bf16x8*)((char*)sAh + ao);
        bf16x8 al = *(const bf16x8*)((char*)sAl + ao);
        bf16x8 bh = ldg8u(wtH + brow + ko);
        bf16x8 bl = ldg8u(wtL + brow + ko);
        acc0 = MFMA(ah, bh, acc0);
        acc1 = MFMA(ah, bl, acc1);
        acc2 = MFMA(al, bh, acc2);
      }
    }

    #pragma unroll
    for (int q = 0; q < 16; q++){
      int rowt = (q&3) + 8*(q>>2) + 4*kp;
      int m = wm*32 + rowt;
      int y  = 2*(t0 + m/SW) + p2;
      int xs = m % SW;
      int xp = OUTPAD ? (2*xs + q2 + 1) : (2*xs + q2);
      size_t base = (((size_t)n*OUTH + y)*OW + xp)*OC + ocl;
      float v = fmaxf(fmaf(acc0[q] + acc1[q] + acc2[q], bn_s1, bn_s2), 0.f);
      ushort h = f2bf(v);
      oH[base] = h;
      if constexpr (OMODE == 0){
        oL[base] = f2bf(v - bf2f(h));
      }
    }
  }
}

// ---------------------------------------------------------------------------
// convT4: 64->1ch + sigmoid + recon-loss. D3 single bf16 plane.
// ---------------------------------------------------------------------------
__global__ __launch_bounds__(256) void dec_convT4(
    const ushort* __restrict__ d3, const float* __restrict__ w4,
    const float* __restrict__ db4, const float* __restrict__ xref,
    float* __restrict__ recon, float* __restrict__ loss)
{
  __shared__ __align__(16) float sT[10*10*68];
  __shared__ __align__(16) float sWt[16*64];
  __shared__ float red[4];
  int b = blockIdx.x;
  int t = b & 255, n = b >> 8;
  int ty = t >> 4, tx = t & 15;
  int y0 = ty*16, x0 = tx*16;
  int r0 = y0/2 - 1, c0 = x0/2 - 1;
  int tid = threadIdx.x;

  *(float4*)&sWt[tid*4] = *(const float4*)(w4 + tid*4);

  const ushort* base = d3 + (size_t)n*128*128*64;
  for (int e = tid; e < 800; e += 256){
    int rr = e/80; int rem = e%80; int cc = rem/8; int c8 = (rem%8)*8;
    int gr = r0+rr, gc = c0+cc;
    short8 v = {0,0,0,0,0,0,0,0};
    if ((unsigned)gr<128u && (unsigned)gc<128u)
      v = *(const short8*)(base + ((size_t)gr*128+gc)*64 + c8);
    float* dst = &sT[(rr*10+cc)*68 + c8];
    float4 f0, f1;
    f0.x = bf2f((ushort)v[0]); f0.y = bf2f((ushort)v[1]);
    f0.z = bf2f((ushort)v[2]); f0.w = bf2f((ushort)v[3]);
    f1.x = bf2f((ushort)v[4]); f1.y = bf2f((ushort)v[5]);
    f1.z = bf2f((ushort)v[6]); f1.w = bf2f((ushort)v[7]);
    *(float4*)dst     = f0;
    *(float4*)(dst+4) = f1;
  }
  __syncthreads();

  int sy = tid>>4, sx = tid&15;
  int p = sy&1, q = sx&1;
  int lr0 = (sy>>1)+p, lc0 = (sx>>1)+q;
  int par = p*2+q;
  float4 a4 = {0,0,0,0};
  #pragma unroll
  for (int a=0;a<2;a++){
    #pragma unroll
    for (int bb=0;bb<2;bb++){
      const float* ip = &sT[((lr0+a)*10 + lc0+bb)*68];
      const float* wp = &sWt[(par*4+a*2+bb)*64];
      #pragma unroll
      for (int c=0;c<64;c+=4){
        float4 v  = *(const float4*)(ip+c);
        float4 wv = *(const float4*)(wp+c);
        a4.x = fmaf(v.x, wv.x, a4.x);
        a4.y = fmaf(v.y, wv.y, a4.y);
        a4.z = fmaf(v.z, wv.z, a4.z);
        a4.w = fmaf(v.w, wv.w, a4.w);
      }
    }
  }
  float acc = (a4.x + a4.y) + (a4.z + a4.w);
  float v = acc + db4[0];
  float rcn = 1.f/(1.f + __expf(-v));
  int y = y0+sy, x = x0+sx;
  size_t oi = (size_t)n*65536 + (size_t)y*256 + x;
  recon[oi] = rcn;
  float d = rcn - xref[oi];
  float s2 = wred64(d*d);
  if ((tid & 63)==0) red[tid>>6] = s2;
  __syncthreads();
  if (tid==0) atomicAdd(loss + 0, red[0]+red[1]+red[2]+red[3]);
}

// ---------------------------------------------------------------------------
__global__ __launch_bounds__(256) void k_final(
    const float* __restrict__ avgs, const unsigned int* __restrict__ cnt,
    const float* __restrict__ cluster, const float* __restrict__ loss,
    float* __restrict__ dout)
{
  __shared__ float red[3][4];
  int tid = threadIdx.x;
  float e1=0.f, e2=0.f, ac=0.f;
  for (int j=tid; j<8192; j+=256){
    float a = avgs[j] * (1.f/8192.f);
    e1 += a * __logf(a + 1e-10f);
    float h = (float)cnt[j] * (1.f/8192.f);
    e2 += h * __logf(h + 1e-10f);
    ac += (cluster[j] > 1.f) ? 1.f : 0.f;
  }
  e1 = wred64(e1); e2 = wred64(e2); ac = wred64(ac);
  int wv = tid >> 6;
  if ((tid & 63)==0){ red[0][wv]=e1; red[1][wv]=e2; red[2][wv]=ac; }
  __syncthreads();
  if (tid==0){
    float s1 = red[0][0]+red[0][1]+red[0][2]+red[0][3];
    float s2 = red[1][0]+red[1][1]+red[1][2]+red[1][3];
    float s3 = red[2][0]+red[2][1]+red[2][2]+red[2][3];
    float ue = -s1;
    dout[O_RLOSS]  = loss[0] * (1.f/2097152.f);
    float cc = loss[1] * (1.f/524288.f);
    dout[O_COMMIT] = cc;
    dout[O_CB]     = cc;
    dout[O_DIV]    = -ue / 9.010913347279288f;
    dout[O_UE]     = ue;
    dout[O_PERP]   = __expf(-s2);
    dout[O_ACT]    = s3;
  }
}

// ---------------------------------------------------------------------------
extern "C" void kernel_launch(void* const* d_in, const int* in_sizes, int n_in,
                              void* d_out, int out_size, void* d_ws, size_t ws_size,
                              hipStream_t stream)
{
  (void)in_sizes; (void)n_in; (void)out_size; (void)ws_size;
  const float* x     = (const float*)d_in[0];
  const float* ew1   = (const float*)d_in[1];
  const float* eb1   = (const float*)d_in[2];
  const float* bn1s  = (const float*)d_in[3];
  const float* bn1b  = (const float*)d_in[4];
  const float* ew2   = (const float*)d_in[5];
  const float* eb2   = (const float*)d_in[6];
  const float* bn2s  = (const float*)d_in[7];
  const float* bn2b  = (const float*)d_in[8];
  const float* ew3   = (const float*)d_in[9];
  const float* eb3   = (const float*)d_in[10];
  const float* bn3s  = (const float*)d_in[11];
  const float* bn3b  = (const float*)d_in[12];
  const float* ew4   = (const float*)d_in[13];
  const float* eb4   = (const float*)d_in[14];
  const float* embed = (const float*)d_in[15];
  const float* clsz  = (const float*)d_in[16];
  const float* dw1   = (const float*)d_in[17];
  const float* db1   = (const float*)d_in[18];
  const float* dbn1s = (const float*)d_in[19];
  const float* dbn1b = (const float*)d_in[20];
  const float* dw2   = (const float*)d_in[21];
  const float* db2   = (const float*)d_in[22];
  const float* dbn2s = (const float*)d_in[23];
  const float* dbn2b = (const float*)d_in[24];
  const float* dw3   = (const float*)d_in[25];
  const float* db3   = (const float*)d_in[26];
  const float* dbn3s = (const float*)d_in[27];
  const float* dbn3b = (const float*)d_in[28];
  const float* dw4   = (const float*)d_in[29];
  const float* db4   = (const float*)d_in[30];

  float* out = (float*)d_out;
  uint8_t* wsb = (uint8_t*)d_ws;

  float*  A1   = (float*)(wsb + WS_R1);
  ushort* D3b  = (ushort*)(wsb + WS_R1);
  ushort* A3h  = (ushort*)(wsb + A3H_OFF);
  ushort* A3m  = (ushort*)(wsb + A3M_OFF);
  ushort* A3l  = (ushort*)(wsb + A3L_OFF);
  float*  Pp   = (float*)(wsb + PP_OFF);
  float*  Mt   = (float*)(wsb + MT_OFF);
  float*  partA= (float*)(wsb + PARTA_OFF);
  ushort* A2h  = (ushort*)(wsb + A2H_OFF);
  ushort* A2m  = (ushort*)(wsb + A2M_OFF);
  ushort* A2l  = (ushort*)(wsb + A2L_OFF);
  ushort* eH   = (ushort*)(wsb + EH_OFF);
  ushort* eM   = (ushort*)(wsb + EM_OFF);
  ushort* eL   = (ushort*)(wsb + EL_OFF);
  ushort* fH   = (ushort*)(wsb + FH_OFF);
  ushort* fM   = (ushort*)(wsb + FM_OFF);
  ushort* fL   = (ushort*)(wsb + FL_OFF);
  ushort* D1h  = (ushort*)(wsb + D1H_OFF);
  ushort* D1l  = (ushort*)(wsb + D1L_OFF);
  ushort* D2h  = (ushort*)(wsb + D2H_OFF);
  ushort* D2l  = (ushort*)(wsb + D2L_OFF);
  float*  flat = (float*)(wsb + WS_FLAT);
  ushort* zqPh = (ushort*)(wsb + WS_ZQP);
  ushort* zqPl = (ushort*)(wsb + WS_ZQP + 1179648ull);

  ushort* wE2h = (ushort*)(wsb + WT_E2);
  ushort* wE2m = wE2h + 65536;  ushort* wE2l = wE2m + 65536;
  ushort* wE3h = (ushort*)(wsb + WT_E3);
  ushort* wE3m = wE3h + 131072; ushort* wE3l = wE3m + 131072;
  ushort* wE4h = (ushort*)(wsb + WT_E4);
  ushort* wE4m = wE4h + 131072; ushort* wE4l = wE4m + 131072;
  ushort* wD1h = (ushort*)(wsb + WT_D1);
  ushort* wD1l = wD1h + 131072;
  ushort* wD2h = (ushort*)(wsb + WT_D2);
  ushort* wD2l = wD2h + 131072;
  ushort* wD3h = (ushort*)(wsb + WT_D3);
  ushort* wD3l = wD3h + 65536;
  float*  w4   = (float*)(wsb + WS_W4);

  unsigned long long* rmp = (unsigned long long*)(wsb + ST_RMP);
  unsigned int* cnt = (unsigned int*)(wsb + ST_CNT);
  float* avgs   = (float*)(wsb + ST_AVGS);
  float* rowzi  = (float*)(wsb + ST_ROWZI);
  float* codesq = (float*)(wsb + ST_CODESQ);
  float* loss   = (float*)(wsb + ST_LOSS);
  float* rowm   = (float*)(wsb + ST_ROWM);

  dim3 B(256);
  dim3 B5(512);

  k_prep<<<3236, B, 0, stream>>>(
      ew2, ew3, ew4, dw1, dw2, dw3, dw4,
      wE2h, wE2m, wE2l, wE3h, wE3m, wE3l, wE4h, wE4m, wE4l,
      wD1h, wD1l, wD2h, wD2l, wD3h, wD3l, w4,
      (unsigned*)A2h, (unsigned*)A2m, (unsigned*)A2l,
      (unsigned*)zqPh, (unsigned*)zqPl,
      cnt, rmp, loss);

  // encoder
  enc_conv1<<<2048, B, 0, stream>>>(x, ew1, eb1, bn1s, bn1b, A1);
  enc_conv<64,64,64,64,128,128,false,0,0><<<2048, B5, 0, stream>>>(
      A1, nullptr, nullptr, nullptr, wE2h, wE2m, wE2l, eb2, bn2s, bn2b,
      nullptr, A2h, A2m, A2l, 1);
  k_zpadA3<<<512, B, 0, stream>>>((unsigned*)A3h, (unsigned*)A3m, (unsigned*)A3l);
  enc_conv<64,128,32,32,64,64,true,1,0><<<1024, B5, 0, stream>>>(
      nullptr, A2h, A2m, A2l, wE3h, wE3m, wE3l, eb3, bn3s, bn3b,
      nullptr, A3h, A3m, A3l, 2);
  k_eprep<<<4096, B, 0, stream>>>(embed, eH, eM, eL, codesq);
  enc_conv<128,64,16,16,32,32,true,1,1><<<128, B5, 0, stream>>>(
      nullptr, A3h, A3m, A3l, wE4h, wE4m, wE4l, eb4, eb4, eb4,
      flat, fH, fM, fL, 1);

  // VQ
  vq_min<<<4096, B, 0, stream>>>(fH, fM, fL, eH, eM, eL, codesq, rmp, Pp, Mt);
  k_rowz2<<<32, B, 0, stream>>>(rmp, Pp, Mt, rowzi, rowm);
  vq_avg<<<4096, B, 0, stream>>>(fH, fM, fL, eH, eM, eL, codesq, rowm, rowzi, partA);
  k_avgred<<<32, B, 0, stream>>>(partA, avgs);

  vq_post<<<3072, B, 0, stream>>>(flat, embed, rmp, out + O_CODES, out + O_ZQ,
                                  zqPh, zqPl, loss, cnt,
                                  (unsigned*)D1h, (unsigned*)D1l,
                                  (unsigned*)D2h, (unsigned*)D2l);

  // decoder (parity-merged, direct-store epilogue)
  dec_convT_m<64,128,16,16,true,0,4><<<256, B, 0, stream>>>(
      zqPh, zqPl, wD1h, wD1l, db1, dbn1s, dbn1b, D1h, D1l, 2);
  dec_convT_m<128,64,32,32,true,0,2><<<1024, B, 0, stream>>>(
      D1h, D1l, wD2h, wD2l, db2, dbn2s, dbn2b, D2h, D2l, 1);
  dec_convT_m<64,64,64,64,false,2,4><<<2048, B, 0, stream>>>(
      D2h, D2l, wD3h, wD3l, db3, dbn3s, dbn3b, D3b, nullptr, 1);
  dec_convT4<<<8192, B, 0, stream>>>(D3b, w4, db4, x, out + O_RECON, loss);

  k_final<<<1, B, 0, stream>>>(avgs, cnt, clsz, loss, out);
}

// Round 17
// 906.124 us; speedup vs baseline: 1.0327x; 1.0327x over previous
//
#include <hip/hip_runtime.h>
#include <cstdint>
#include <cstddef>

// ---------------------------------------------------------------------------
// VQ-VAE forward, MFMA split-bf16 (gfx950), round 17 = round 15 verbatim
// (revert of round 16's 8-wave K-split, which regressed: same 2 blocks/CU
// LDS cap, but barriers now sync 8 phase-locked waves).
// Final structure: 1959us (fp32 baseline) -> 906us across 16 rounds.
// ---------------------------------------------------------------------------

#define DEVI __device__ __forceinline__

typedef short  short8 __attribute__((ext_vector_type(8)));
typedef __bf16 bf16x8 __attribute__((ext_vector_type(8)));
typedef float  f32x16 __attribute__((ext_vector_type(16)));

DEVI f32x16 MFMA(bf16x8 a, bf16x8 b, f32x16 c){
  return __builtin_amdgcn_mfma_f32_32x32x16_bf16(a, b, c, 0, 0, 0);
}

DEVI ushort f2bf(float f){
  unsigned u = __float_as_uint(f);
  unsigned r = (u + 0x7FFFu + ((u >> 16) & 1u)) >> 16;
  return (ushort)r;
}
DEVI float bf2f(ushort h){ return __uint_as_float(((unsigned)h) << 16); }

union U8 { short8 s; bf16x8 b; };
DEVI bf16x8 ldg8u(const ushort* p){
  U8 u; u.s = *(const short8*)p; return u.b;
}

DEVI float wred64(float v){
  #pragma unroll
  for (int off=32; off>0; off>>=1) v += __shfl_down(v, off, 64);
  return v;
}

// ---- output layout (float32 elements) ----
#define O_RECON     0
#define O_RLOSS     2097152
#define O_CODES     2097153
#define O_ZQ        2105345
#define O_COMMIT    2629633
#define O_CB        2629634
#define O_DIV       2629635
#define O_UE        2629636
#define O_PERP      2629637
#define O_ACT       2629638

// ---- workspace layout (bytes) ----
#define WS_R1       0ull
#define A3H_OFF     0ull
#define A3M_OFF     8912896ull
#define A3L_OFF     17825792ull
#define PP_OFF      33554432ull
#define MT_OFF      37748736ull
#define PARTA_OFF   41943040ull
#define A2H_OFF     134217728ull
#define A2M_OFF     151519232ull
#define A2L_OFF     168820736ull
#define EH_OFF      134217728ull
#define EM_OFF      135266304ull
#define EL_OFF      136314880ull
#define FH_OFF      137363456ull
#define FM_OFF      138412032ull
#define FL_OFF      139460608ull
#define D2H_OFF     134217728ull
#define D2L_OFF     151519232ull
#define D1H_OFF     168820736ull
#define D1L_OFF     177733632ull
#define WS_FLAT     186646528ull
#define WS_ZQP      188743680ull
#define WS_WT       191102976ull
#define WT_E2       (WS_WT)
#define WT_E3       (WT_E2 + 393216ull)
#define WT_E4       (WT_E3 + 786432ull)
#define WT_D1       (WT_E4 + 786432ull)
#define WT_D2       (WT_D1 + 524288ull)
#define WT_D3       (WT_D2 + 524288ull)
#define WS_W4       (WT_D3 + 262144ull)
#define WS_STATS    (WS_W4 + 4096ull)
#define ST_RMP      (WS_STATS)
#define ST_CNT      (ST_RMP + 65536ull)
#define ST_AVGS     (ST_CNT + 32768ull)
#define ST_ROWZI    (ST_AVGS + 32768ull)
#define ST_CODESQ   (ST_ROWZI + 32768ull)
#define ST_LOSS     (ST_CODESQ + 32768ull)
#define ST_ROWM     (ST_LOSS + 32768ull)

// ---------------------------------------------------------------------------
DEVI void wsplit_body(int i, const float* src, ushort* dh, ushort* dm,
                      ushort* dl, int OC, int CIN, int isT, int three)
{
  if (i >= 16*OC*CIN) return;
  int cin = i % CIN; int t = i / CIN; int oc = t % OC; int tap = t / OC;
  int st;
  if (isT){
    int pq = tap>>2, ab = tap&3;
    int p = pq>>1, q = pq&1, a = ab>>1, b = ab&1;
    st = (p + 2*a)*4 + (q + 2*b);
  } else st = tap;
  float v = src[((size_t)oc*CIN + cin)*16 + st];
  ushort h = f2bf(v); float r = v - bf2f(h);
  if (three){
    ushort m = f2bf(r); float r2 = r - bf2f(m);
    dm[i] = m; dl[i] = f2bf(r2);
  } else {
    dl[i] = f2bf(r);
  }
  dh[i] = h;
}

DEVI void zpad_body(int i, unsigned* b0, unsigned* b1, unsigned* b2,
                    int rows, int Wp, int cwords)
{
  int total = rows*2*cwords;
  if (i >= total) return;
  int pos = i / cwords, cw = i % cwords;
  int row = pos >> 1, side = pos & 1;
  size_t w = ((size_t)row*Wp + (side ? (Wp-1) : 0))*cwords + cw;
  b0[w] = 0u;
  if (b1) b1[w] = 0u;
  if (b2) b2[w] = 0u;
}

// one launch: init + all weight splits + w4prep + A2/zqP pad zeroing
__global__ __launch_bounds__(256) void k_prep(
    const float* __restrict__ ew2, const float* __restrict__ ew3,
    const float* __restrict__ ew4, const float* __restrict__ dw1,
    const float* __restrict__ dw2, const float* __restrict__ dw3,
    const float* __restrict__ dw4,
    ushort* wE2h, ushort* wE2m, ushort* wE2l,
    ushort* wE3h, ushort* wE3m, ushort* wE3l,
    ushort* wE4h, ushort* wE4m, ushort* wE4l,
    ushort* wD1h, ushort* wD1l, ushort* wD2h, ushort* wD2l,
    ushort* wD3h, ushort* wD3l, float* w4,
    unsigned* A2h, unsigned* A2m, unsigned* A2l,
    unsigned* zqPh, unsigned* zqPl,
    unsigned int* cnt, unsigned long long* rmp, float* loss)
{
  int b = blockIdx.x, tid = threadIdx.x;
  if (b < 32){
    int i = b*256 + tid;
    if (i < 8192){ cnt[i]=0u; rmp[i]=0xFFFFFFFFFFFFFFFFull; }
    if (i < 8) loss[i]=0.f;
  } else if (b < 288){
    wsplit_body((b-32)*256 + tid, ew2, wE2h, wE2m, wE2l, 64, 64, 0, 1);
  } else if (b < 800){
    wsplit_body((b-288)*256 + tid, ew3, wE3h, wE3m, wE3l, 128, 64, 0, 1);
  } else if (b < 1312){
    wsplit_body((b-800)*256 + tid, ew4, wE4h, wE4m, wE4l, 64, 128, 0, 1);
  } else if (b < 1824){
    wsplit_body((b-1312)*256 + tid, dw1, wD1h, nullptr, wD1l, 128, 64, 1, 0);
  } else if (b < 2336){
    wsplit_body((b-1824)*256 + tid, dw2, wD2h, nullptr, wD2l, 64, 128, 1, 0);
  } else if (b < 2592){
    wsplit_body((b-2336)*256 + tid, dw3, wD3h, nullptr, wD3l, 64, 64, 1, 0);
  } else if (b < 2596){
    int i = (b-2592)*256 + tid;
    if (i < 1024){
      int c = i & 63; int t16 = i >> 6;
      int pq = t16 >> 2, ab = t16 & 3;
      int p = pq>>1, q = pq&1, a = ab>>1, bb = ab&1;
      w4[i] = dw4[(size_t)c*16 + (p+2*a)*4 + (q+2*bb)];
    }
  } else if (b < 3108){
    zpad_body((b-2596)*256 + tid, A2h, A2m, A2l, 32*64, 66, 32);
  } else {
    zpad_body((b-3108)*256 + tid, zqPh, zqPl, nullptr, 32*16, 18, 32);
  }
}

__global__ __launch_bounds__(256) void k_zpadA3(unsigned* b0, unsigned* b1,
                                                unsigned* b2)
{
  zpad_body(blockIdx.x*256 + threadIdx.x, b0, b1, b2, 32*32, 34, 64);
}

// merged: embed split (blocks 0..2047) + codesq (blocks 2048..4095)
__global__ __launch_bounds__(256) void k_eprep(
    const float* __restrict__ embed,
    ushort* __restrict__ dh, ushort* __restrict__ dm, ushort* __restrict__ dl,
    float* __restrict__ codesq)
{
  int b = blockIdx.x;
  if (b < 2048){
    int i = b*256 + threadIdx.x;
    float v = embed[i];
    ushort h = f2bf(v); float r1 = v - bf2f(h);
    ushort m = f2bf(r1); float r2 = r1 - bf2f(m);
    dh[i] = h; dm[i] = m; dl[i] = f2bf(r2);
  } else {
    int j = (b-2048)*4 + (threadIdx.x>>6);
    int c = threadIdx.x & 63;
    float e = embed[(size_t)j*64 + c];
    float s = wred64(e*e);
    if (c==0) codesq[j] = s;
  }
}

// ---------------------------------------------------------------------------
// conv1: 1->64ch, k4 s2 p1, direct fp32, writes NHWC fp32 [32][128][128][64]
// ---------------------------------------------------------------------------
__global__ __launch_bounds__(256) void enc_conv1(
    const float* __restrict__ x, const float* __restrict__ w,
    const float* __restrict__ cb_, const float* __restrict__ bns,
    const float* __restrict__ bnb, float* __restrict__ out)
{
  __shared__ __align__(16) float sIn[34][36];
  __shared__ __align__(16) float sW[64][16];
  int b = blockIdx.x;
  int t = b & 63, n = b >> 6;
  int ty = t >> 3, tx = t & 7;
  int oy0 = ty*16, ox0 = tx*16;
  int iy0 = 2*oy0 - 1, ix0 = 2*ox0 - 1;
  int tid = threadIdx.x;
  int spg = tid & 31, og = tid >> 5;
  int sy = spg >> 1, x0 = (spg & 1)*8;

  if (tid < 64){
    const float* wp = w + tid*16;
    *(float4*)&sW[tid][0]  = *(const float4*)(wp);
    *(float4*)&sW[tid][4]  = *(const float4*)(wp+4);
    *(float4*)&sW[tid][8]  = *(const float4*)(wp+8);
    *(float4*)&sW[tid][12] = *(const float4*)(wp+12);
  }
  for (int e = tid; e < 34*34; e += 256){
    int rr = e/34, cc = e%34;
    int iy = iy0+rr, ix = ix0+cc;
    float v = 0.f;
    if ((unsigned)iy < 256u && (unsigned)ix < 256u)
      v = x[(size_t)n*65536 + iy*256 + ix];
    sIn[rr][cc] = v;
  }
  __syncthreads();

  float acc[8][8];
  #pragma unroll
  for (int j=0;j<8;j++)
    #pragma unroll
    for (int xi=0;xi<8;xi++) acc[j][xi]=0.f;

  #pragma unroll
  for (int ky=0; ky<4; ky++){
    int riy = 2*sy + ky;
    float seg[20];
    #pragma unroll
    for (int i=0;i<5;i++){
      float4 v = *(const float4*)&sIn[riy][2*x0 + 4*i];
      seg[4*i+0]=v.x; seg[4*i+1]=v.y; seg[4*i+2]=v.z; seg[4*i+3]=v.w;
    }
    #pragma unroll
    for (int j=0;j<8;j++){
      float4 w4v = *(const float4*)&sW[og*8+j][ky*4];
      #pragma unroll
      for (int xi=0; xi<8; xi++){
        acc[j][xi] = fmaf(seg[2*xi+0], w4v.x,
                     fmaf(seg[2*xi+1], w4v.y,
                     fmaf(seg[2*xi+2], w4v.z,
                     fmaf(seg[2*xi+3], w4v.w, acc[j][xi]))));
      }
    }
  }

  float sc[8], sh[8];
  #pragma unroll
  for (int j=0;j<8;j++){
    int oc = og*8+j;
    sc[j] = bns[oc];
    sh[j] = fmaf(cb_[oc], sc[j], bnb[oc]);
  }
  int oy = oy0 + sy;
  #pragma unroll
  for (int xi=0; xi<8; xi++){
    int oxg = ox0 + x0 + xi;
    float* op = out + (((size_t)n*128 + oy)*128 + oxg)*64 + og*8;
    float4 q0, q1;
    q0.x = fmaxf(fmaf(acc[0][xi], sc[0], sh[0]), 0.f);
    q0.y = fmaxf(fmaf(acc[1][xi], sc[1], sh[1]), 0.f);
    q0.z = fmaxf(fmaf(acc[2][xi], sc[2], sh[2]), 0.f);
    q0.w = fmaxf(fmaf(acc[3][xi], sc[3], sh[3]), 0.f);
    q1.x = fmaxf(fmaf(acc[4][xi], sc[4], sh[4]), 0.f);
    q1.y = fmaxf(fmaf(acc[5][xi], sc[5], sh[5]), 0.f);
    q1.z = fmaxf(fmaf(acc[6][xi], sc[6], sh[6]), 0.f);
    q1.w = fmaxf(fmaf(acc[7][xi], sc[7], sh[7]), 0.f);
    *(float4*)op     = q0;
    *(float4*)(op+4) = q1;
  }
}

// ---------------------------------------------------------------------------
// Encoder conv k4 s2 p1 tap-GEMM, 6-term MFMA, quad-acc, B reg-prefetch
// (coalesced cooperative prefetch -> LDS), DIRECT epilogue stores.
// ---------------------------------------------------------------------------
template<int CIN, int OC, int OUTW, int OUTH, int INW, int INH, bool XPAD,
         int INMODE, int OUTMODE>
__global__ __launch_bounds__(256) void enc_conv(
    const float* __restrict__ in,
    const ushort* __restrict__ aH, const ushort* __restrict__ aM,
    const ushort* __restrict__ aL,
    const ushort* __restrict__ wtH, const ushort* __restrict__ wtM,
    const ushort* __restrict__ wtL,
    const float* __restrict__ cb_, const float* __restrict__ bns,
    const float* __restrict__ bnb,
    float* __restrict__ outF,
    ushort* __restrict__ oH, ushort* __restrict__ oM, ushort* __restrict__ oL,
    int nOcg)
{
  constexpr int INWP  = (INMODE==1) ? (INW+2) : (XPAD ? (INW+2) : INW);
  constexpr int WP    = INW + 2;
  constexpr int NROWS = 64 / OUTW;
  constexpr int AELEM = NROWS * WP * CIN;
  constexpr int BCIN  = (CIN > 64) ? 64 : CIN;
  constexpr int BELEM = 64 * BCIN;
  constexpr int NCH   = CIN / BCIN;
  constexpr int NSTG  = 16 * NCH;
  constexpr int PFI   = BELEM / 8 / 256;

  __shared__ __align__(16) ushort sAh[AELEM], sAm[AELEM], sAl[AELEM];
  __shared__ __align__(16) ushort sBh[BELEM], sBm[BELEM], sBl[BELEM];

  int b = blockIdx.x;
  int ocg = b % nOcg; b /= nOcg;
  int yb  = b % (OUTH/NROWS); b /= (OUTH/NROWS);
  int n = b;
  int oy0 = yb * NROWS, oc0 = ocg * 64;

  int tid = threadIdx.x;
  int l = tid & 63, wave = tid >> 6;
  int wm = wave >> 1, wn = wave & 1;
  int r = l & 31, kp = l >> 5;
  int idx = wm*32 + r;
  int oy_off = idx / OUTW, ox = idx % OUTW;

  int pfoc[PFI], pfc8[PFI];
  #pragma unroll
  for (int it=0; it<PFI; it++){
    int c = tid + it*256;
    pfoc[it] = c / (BCIN/8);
    pfc8[it] = (c % (BCIN/8)) * 8;
  }
  short8 pf0[PFI], pf1[PFI], pf2[PFI];
  {
    #pragma unroll
    for (int it=0; it<PFI; it++){
      size_t off = ((size_t)oc0 + pfoc[it])*CIN + pfc8[it];
      pf0[it] = *(const short8*)(wtH + off);
      pf1[it] = *(const short8*)(wtM + off);
      pf2[it] = *(const short8*)(wtL + off);
    }
  }

  f32x16 acc0, acc1, acc2, acc3;
  #pragma unroll
  for (int i=0;i<16;i++){ acc0[i]=0.f; acc1[i]=0.f; acc2[i]=0.f; acc3[i]=0.f; }

  const size_t nbase = (size_t)n * INH * INWP * CIN;
  int sidx = 0;

  for (int ky = 0; ky < 4; ky++){
    __syncthreads();
    for (int c = tid; c < AELEM/8; c += 256){
      int j  = c / (WP*CIN/8);
      int rm = c % (WP*CIN/8);
      int lx = rm / (CIN/8);
      int c8 = (rm % (CIN/8)) * 8;
      int iy = 2*(oy0 + j) - 1 + ky;
      bool ok = (unsigned)iy < (unsigned)INH;
      unsigned off = (unsigned)(((j*WP + lx)*CIN + c8)*2) ^ ((((unsigned)lx>>1)&15u)<<4);
      if constexpr (INMODE == 0){
        int gx = XPAD ? lx : (lx - 1);
        if (!XPAD) ok = ok && ((unsigned)gx < (unsigned)INW);
        float4 v0 = {0,0,0,0}, v1 = {0,0,0,0};
        if (ok){
          const float* s = in + nbase + ((size_t)iy*INWP + gx)*CIN + c8;
          v0 = *(const float4*)s; v1 = *(const float4*)(s+4);
        }
        float vv[8] = {v0.x,v0.y,v0.z,v0.w,v1.x,v1.y,v1.z,v1.w};
        short8 hh, mm, ll;
        #pragma unroll
        for (int e=0;e<8;e++){
          ushort h = f2bf(vv[e]); float r1 = vv[e] - bf2f(h);
          ushort m = f2bf(r1);    float r2 = r1 - bf2f(m);
          hh[e] = (short)h; mm[e] = (short)m; ll[e] = (short)f2bf(r2);
        }
        *(short8*)((char*)sAh + off) = hh;
        *(short8*)((char*)sAm + off) = mm;
        *(short8*)((char*)sAl + off) = ll;
      } else {
        short8 vh = {0,0,0,0,0,0,0,0}, vm = vh, vl = vh;
        if (ok){
          size_t s = nbase + ((size_t)iy*INWP + lx)*CIN + c8;
          vh = *(const short8*)(aH + s);
          vm = *(const short8*)(aM + s);
          vl = *(const short8*)(aL + s);
        }
        *(short8*)((char*)sAh + off) = vh;
        *(short8*)((char*)sAm + off) = vm;
        *(short8*)((char*)sAl + off) = vl;
      }
    }
    for (int kx = 0; kx < 4; kx++){
      for (int chi = 0; chi < NCH; chi++){
        int ch = chi * BCIN;
        __syncthreads();
        #pragma unroll
        for (int it=0; it<PFI; it++){
          unsigned off = (unsigned)((pfoc[it]*BCIN + pfc8[it])*2)
                         ^ (((unsigned)pfoc[it]&15u)<<4);
          *(short8*)((char*)sBh + off) = pf0[it];
          *(short8*)((char*)sBm + off) = pf1[it];
          *(short8*)((char*)sBl + off) = pf2[it];
        }
        __syncthreads();
        if (sidx + 1 < NSTG){
          int ns = sidx + 1;
          int ntap = ns / NCH, nchi = ns % NCH;
          #pragma unroll
          for (int it=0; it<PFI; it++){
            size_t off = ((size_t)ntap*OC + oc0 + pfoc[it])*CIN
                         + nchi*BCIN + pfc8[it];
            pf0[it] = *(const short8*)(wtH + off);
            pf1[it] = *(const short8*)(wtM + off);
            pf2[it] = *(const short8*)(wtL + off);
          }
        }
        sidx++;
        int lx = 2*ox + kx;
        unsigned asw  = ((((unsigned)lx>>1)&15u)<<4);
        unsigned alin = (unsigned)(((oy_off*WP + lx)*CIN)*2);
        int ocl = wn*32 + r;
        unsigned bsw  = (((unsigned)ocl&15u)<<4);
        unsigned blin = (unsigned)((ocl*BCIN)*2);
        #pragma unroll
        for (int ct = 0; ct < BCIN/16; ct++){
          unsigned kbA = (unsigned)((ch + ct*16 + kp*8)*2);
          unsigned kbB = (unsigned)((ct*16 + kp*8)*2);
          unsigned ao = (alin + kbA) ^ asw;
          unsigned bo = (blin + kbB) ^ bsw;
          bf16x8 ah = *(const bf16x8*)((char*)sAh + ao);
          bf16x8 am = *(const bf16x8*)((char*)sAm + ao);
          bf16x8 al = *(const bf16x8*)((char*)sAl + ao);
          bf16x8 bh = *(const bf16x8*)((char*)sBh + bo);
          bf16x8 bm = *(const bf16x8*)((char*)sBm + bo);
          bf16x8 bl = *(const bf16x8*)((char*)sBl + bo);
          acc0 = MFMA(ah, bh, acc0);
          acc1 = MFMA(ah, bm, acc1);
          acc2 = MFMA(am, bh, acc2);
          acc3 = MFMA(ah, bl, acc3);
          acc0 = MFMA(am, bm, acc0);
          acc1 = MFMA(al, bh, acc1);
        }
      }
    }
  }
  // ---- direct epilogue: lane holds oc; q indexes spatial rows ----
  {
    int oce = oc0 + wn*32 + r;
    if constexpr (OUTMODE == 1){
      float cbv = cb_[oce];
      #pragma unroll
      for (int q = 0; q < 16; q++){
        int rowt = (q&3) + 8*(q>>2) + 4*kp;
        int m = wm*32 + rowt;
        int oyg = oy0 + m / OUTW;
        int oxg = m % OUTW;
        size_t row = (size_t)n*256 + oyg*16 + oxg;
        float v = (acc0[q] + acc1[q]) + (acc2[q] + acc3[q]) + cbv;
        outF[row*64 + oce] = v;
        ushort h = f2bf(v); float r1 = v - bf2f(h);
        ushort mm = f2bf(r1); float r2 = r1 - bf2f(mm);
        oH[row*64 + oce] = h;
        oM[row*64 + oce] = mm;
        oL[row*64 + oce] = f2bf(r2);
      }
    } else {
      float s1 = bns[oce];
      float s2 = fmaf(cb_[oce], s1, bnb[oce]);
      #pragma unroll
      for (int q = 0; q < 16; q++){
        int rowt = (q&3) + 8*(q>>2) + 4*kp;
        int m = wm*32 + rowt;
        int oyg = oy0 + m / OUTW;
        int oxg = m % OUTW;
        size_t pbase = (((size_t)n*OUTH + oyg)*(OUTW+2) + oxg + 1)*OC + oce;
        float v = fmaxf(fmaf((acc0[q] + acc1[q]) + (acc2[q] + acc3[q]), s1, s2), 0.f);
        ushort h = f2bf(v); float r1 = v - bf2f(h);
        ushort mm = f2bf(r1); float r2 = r1 - bf2f(mm);
        oH[pbase] = h;
        oM[pbase] = mm;
        oL[pbase] = f2bf(r2);
      }
    }
  }
}

DEVI float rmp_minval(unsigned long long v){
  unsigned skey = (unsigned)(v >> 32);
  unsigned u = (skey & 0x80000000u) ? (skey ^ 0x80000000u) : ~skey;
  return __uint_as_float(u);
}

// ---------------------------------------------------------------------------
// VQ pass 1, swapped operands (codes in rows), in-register argmin.
// ---------------------------------------------------------------------------
__global__ __launch_bounds__(256) void vq_min(
    const ushort* __restrict__ fH, const ushort* __restrict__ fM,
    const ushort* __restrict__ fL,
    const ushort* __restrict__ eH, const ushort* __restrict__ eM,
    const ushort* __restrict__ eL,
    const float* __restrict__ codesq,
    unsigned long long* __restrict__ rmp,
    float* __restrict__ Pp, float* __restrict__ Mt)
{
  __shared__ __align__(16) ushort sAh[128*64], sAm[128*64], sAl[128*64];
  int cblk = blockIdx.x & 63, fblk = blockIdx.x >> 6;
  int code0 = cblk*128, f0 = fblk*128;
  int tid = threadIdx.x, l = tid&63, wave = tid>>6;
  int wm = wave>>1, wn = wave&1, r = l&31, kp = l>>5;

  for (int c = tid; c < 1024; c += 256){
    int rr = c >> 3, c8 = (c & 7)*8;
    size_t s = (size_t)(code0+rr)*64 + c8;
    unsigned off = (unsigned)((rr*64 + c8)*2) ^ (((unsigned)rr&15u)<<4);
    *(short8*)((char*)sAh + off) = *(const short8*)(eH + s);
    *(short8*)((char*)sAm + off) = *(const short8*)(eM + s);
    *(short8*)((char*)sAl + off) = *(const short8*)(eL + s);
  }
  __syncthreads();

  f32x16 acc[2][2];
  #pragma unroll
  for (int mt=0;mt<2;mt++)
    #pragma unroll
    for (int nt=0;nt<2;nt++)
      #pragma unroll
      for (int i=0;i<16;i++) acc[mt][nt][i]=0.f;

  #pragma unroll
  for (int ks=0; ks<4; ks++){
    unsigned kb = (unsigned)((ks*16 + kp*8)*2);
    int ko = ks*16 + kp*8;
    bf16x8 Ah[2],Am[2],Al[2],Bh[2],Bm[2],Bl[2];
    #pragma unroll
    for (int mt=0;mt<2;mt++){
      int rowi = wm*64 + mt*32 + r;
      unsigned o = ((unsigned)(rowi*128) + kb) ^ (((unsigned)rowi&15u)<<4);
      Ah[mt] = *(const bf16x8*)((char*)sAh + o);
      Am[mt] = *(const bf16x8*)((char*)sAm + o);
      Al[mt] = *(const bf16x8*)((char*)sAl + o);
    }
    #pragma unroll
    for (int nt=0;nt<2;nt++){
      int coli = f0 + wn*64 + nt*32 + r;
      size_t bo = (size_t)coli*64 + ko;
      Bh[nt] = ldg8u(fH + bo);
      Bm[nt] = ldg8u(fM + bo);
      Bl[nt] = ldg8u(fL + bo);
    }
    #pragma unroll
    for (int mt=0;mt<2;mt++)
      #pragma unroll
      for (int nt=0;nt<2;nt++){
        acc[mt][nt] = MFMA(Ah[mt], Bh[nt], acc[mt][nt]);
        acc[mt][nt] = MFMA(Ah[mt], Bm[nt], acc[mt][nt]);
        acc[mt][nt] = MFMA(Am[mt], Bh[nt], acc[mt][nt]);
        acc[mt][nt] = MFMA(Ah[mt], Bl[nt], acc[mt][nt]);
        acc[mt][nt] = MFMA(Am[mt], Bm[nt], acc[mt][nt]);
        acc[mt][nt] = MFMA(Al[mt], Bh[nt], acc[mt][nt]);
      }
  }

  float cqv[2][16];
  #pragma unroll
  for (int mt=0; mt<2; mt++)
    #pragma unroll
    for (int g=0; g<4; g++){
      float4 cv = *(const float4*)(codesq + code0 + wm*64 + mt*32 + 8*g + 4*kp);
      cqv[mt][4*g+0]=cv.x; cqv[mt][4*g+1]=cv.y;
      cqv[mt][4*g+2]=cv.z; cqv[mt][4*g+3]=cv.w;
    }

  #pragma unroll
  for (int nt=0; nt<2; nt++){
    int col = f0 + wn*64 + nt*32 + r;
    unsigned long long kmin = 0xFFFFFFFFFFFFFFFFull;
    #pragma unroll
    for (int mt=0; mt<2; mt++)
      #pragma unroll
      for (int q=0; q<16; q++){
        float d = cqv[mt][q] - 2.f*acc[mt][nt][q];
        int code = code0 + wm*64 + mt*32 + (q&3) + 8*(q>>2) + 4*kp;
        unsigned u = __float_as_uint(d);
        unsigned sgn = (unsigned)((int)u >> 31);
        unsigned skey = u ^ (sgn | 0x80000000u);
        unsigned long long key = (((unsigned long long)skey)<<32) | (unsigned)code;
        if (key < kmin) kmin = key;
      }
    unsigned long long o2 = __shfl_xor(kmin, 32, 64);
    if (o2 < kmin) kmin = o2;
    float mloc = rmp_minval(kmin);
    float p = 0.f;
    #pragma unroll
    for (int mt=0; mt<2; mt++)
      #pragma unroll
      for (int q=0; q<16; q++){
        float d = cqv[mt][q] - 2.f*acc[mt][nt][q];
        p += __expf(mloc - d);
      }
    p += __shfl_xor(p, 32, 64);
    if (kp == 0){
      atomicMin(&rmp[col], kmin);
      size_t pidx = (size_t)col*128 + (size_t)cblk*2 + wm;
      Pp[pidx] = p;
      Mt[pidx] = mloc;
    }
  }
}

// rowz-lite
__global__ __launch_bounds__(256) void k_rowz2(
    const unsigned long long* __restrict__ rmp,
    const float* __restrict__ Pp, const float* __restrict__ Mt,
    float* __restrict__ rowzi, float* __restrict__ rowm)
{
  int row = blockIdx.x*256 + threadIdx.x;
  float mg = rmp_minval(rmp[row]);
  const float* pp = Pp + (size_t)row*128;
  const float* mt = Mt + (size_t)row*128;
  float z = 0.f;
  for (int t = 0; t < 128; t++)
    z = fmaf(__expf(mg - mt[t]), pp[t], z);
  rowzi[row] = 1.f / z;
  rowm[row] = mg;
}

// ---------------------------------------------------------------------------
// VQ pass 2: recompute tiles (original orientation), col partials.
// ---------------------------------------------------------------------------
__global__ __launch_bounds__(256) void vq_avg(
    const ushort* __restrict__ fH, const ushort* __restrict__ fM,
    const ushort* __restrict__ fL,
    const ushort* __restrict__ eH, const ushort* __restrict__ eM,
    const ushort* __restrict__ eL,
    const float* __restrict__ codesq,
    const float* __restrict__ rowm,
    const float* __restrict__ rowzi,
    float* __restrict__ partA)
{
  __shared__ __align__(16) ushort sAh[128*64], sAm[128*64], sAl[128*64];
  __shared__ float colbuf[128];
  int cb = blockIdx.x & 63, rb = blockIdx.x >> 6;
  int row0 = rb*128, c0 = cb*128;
  int tid = threadIdx.x, l = tid&63, wave = tid>>6;
  int wm = wave>>1, wn = wave&1, r = l&31, kp = l>>5;

  if (tid < 128) colbuf[tid] = 0.f;

  for (int c = tid; c < 1024; c += 256){
    int rr = c >> 3, c8 = (c & 7)*8;
    size_t s = (size_t)(row0+rr)*64 + c8;
    unsigned off = (unsigned)((rr*64 + c8)*2) ^ (((unsigned)rr&15u)<<4);
    *(short8*)((char*)sAh + off) = *(const short8*)(fH + s);
    *(short8*)((char*)sAm + off) = *(const short8*)(fM + s);
    *(short8*)((char*)sAl + off) = *(const short8*)(fL + s);
  }
  __syncthreads();

  f32x16 acc[2][2];
  #pragma unroll
  for (int mt=0;mt<2;mt++)
    #pragma unroll
    for (int nt=0;nt<2;nt++)
      #pragma unroll
      for (int i=0;i<16;i++) acc[mt][nt][i]=0.f;

  #pragma unroll
  for (int ks=0; ks<4; ks++){
    unsigned kb = (unsigned)((ks*16 + kp*8)*2);
    int ko = ks*16 + kp*8;
    bf16x8 Ah[2],Am[2],Al[2],Bh[2],Bm[2],Bl[2];
    #pragma unroll
    for (int mt=0;mt<2;mt++){
      int rowi = wm*64 + mt*32 + r;
      unsigned o = ((unsigned)(rowi*128) + kb) ^ (((unsigned)rowi&15u)<<4);
      Ah[mt] = *(const bf16x8*)((char*)sAh + o);
      Am[mt] = *(const bf16x8*)((char*)sAm + o);
      Al[mt] = *(const bf16x8*)((char*)sAl + o);
    }
    #pragma unroll
    for (int nt=0;nt<2;nt++){
      int coli = c0 + wn*64 + nt*32 + r;
      size_t bo = (size_t)coli*64 + ko;
      Bh[nt] = ldg8u(eH + bo);
      Bm[nt] = ldg8u(eM + bo);
      Bl[nt] = ldg8u(eL + bo);
    }
    #pragma unroll
    for (int mt=0;mt<2;mt++)
      #pragma unroll
      for (int nt=0;nt<2;nt++){
        acc[mt][nt] = MFMA(Ah[mt], Bh[nt], acc[mt][nt]);
        acc[mt][nt] = MFMA(Ah[mt], Bm[nt], acc[mt][nt]);
        acc[mt][nt] = MFMA(Am[mt], Bh[nt], acc[mt][nt]);
        acc[mt][nt] = MFMA(Ah[mt], Bl[nt], acc[mt][nt]);
        acc[mt][nt] = MFMA(Am[mt], Bm[nt], acc[mt][nt]);
        acc[mt][nt] = MFMA(Al[mt], Bh[nt], acc[mt][nt]);
      }
  }

  float cq[2];
  cq[0] = codesq[c0 + wn*64 + r];
  cq[1] = codesq[c0 + wn*64 + 32 + r];
  float colacc[2] = {0.f, 0.f};
  #pragma unroll
  for (int mt=0; mt<2; mt++){
    #pragma unroll
    for (int q=0; q<16; q++){
      int rowt = (q&3) + 8*(q>>2) + 4*kp;
      int grow = row0 + wm*64 + mt*32 + rowt;
      float mi = rowm[grow];
      float zi = rowzi[grow];
      #pragma unroll
      for (int nt=0; nt<2; nt++){
        float d = cq[nt] - 2.f*acc[mt][nt][q];
        colacc[nt] = fmaf(__expf(mi - d), zi, colacc[nt]);
      }
    }
  }
  #pragma unroll
  for (int nt=0; nt<2; nt++){
    float o = __shfl_xor(colacc[nt], 32, 64);
    colacc[nt] += o;
    if (l < 32) atomicAdd(&colbuf[wn*64 + nt*32 + r], colacc[nt]);
  }
  __syncthreads();
  if (tid < 128)
    partA[(size_t)rb*8192 + c0 + tid] = colbuf[tid];
}

__global__ __launch_bounds__(256) void k_avgred(const float* __restrict__ partA,
                                                float* __restrict__ avgs)
{
  int j = blockIdx.x*256 + threadIdx.x;
  float s = 0.f;
  for (int rb = 0; rb < 64; rb++)
    s += partA[(size_t)rb*8192 + j];
  avgs[j] = s;
}

// codes, zq, zqP planes, commit SSE, hist. Blocks >= 2048 do D1/D2 pad-zero.
__global__ __launch_bounds__(256) void vq_post(
    const float* __restrict__ flat, const float* __restrict__ embed,
    const unsigned long long* __restrict__ rmp,
    float* __restrict__ out_codes, float* __restrict__ out_zq,
    ushort* __restrict__ zqPh, ushort* __restrict__ zqPl,
    float* __restrict__ loss, unsigned int* __restrict__ cnt,
    unsigned* __restrict__ d1h, unsigned* __restrict__ d1l,
    unsigned* __restrict__ d2h, unsigned* __restrict__ d2l)
{
  int blk = blockIdx.x;
  if (blk >= 2048){
    int zb = blk - 2048;
    if (zb < 512) zpad_body(zb*256 + threadIdx.x, d1h, d1l, nullptr, 32*32, 34, 64);
    else zpad_body((zb-512)*256 + threadIdx.x, d2h, d2l, nullptr, 32*64, 66, 32);
    return;
  }
  int r = blk*4 + (threadIdx.x>>6);
  int c = threadIdx.x & 63;
  unsigned j = (unsigned)(rmp[r] & 0xFFFFFFFFull);
  float e = embed[(size_t)j*64 + c];
  float f = flat[(size_t)r*64 + c];
  int n = r>>8, rem = r&255, gy = rem>>4, gx = rem&15;
  out_zq[(((size_t)n*64 + c)*16 + gy)*16 + gx] = e;
  ushort h = f2bf(e);
  size_t pz = (((size_t)n*16 + gy)*18 + gx + 1)*64 + c;
  zqPh[pz] = h; zqPl[pz] = f2bf(e - bf2f(h));
  float d = f - e;
  float s2 = wred64(d*d);
  if (c==0){
    out_codes[r] = (float)j;
    atomicAdd(cnt + j, 1u);
    atomicAdd(loss + 1, s2);
  }
}

// ---------------------------------------------------------------------------
// PARITY-MERGED decoder convT, 3-term MFMA, TRI-acc, DIRECT epilogue stores.
// ---------------------------------------------------------------------------
template<int CIN, int OC, int SW, int SH, bool OUTPAD, int OMODE, int NPAR>
__global__ __launch_bounds__(256) void dec_convT_m(
    const ushort* __restrict__ inH, const ushort* __restrict__ inL,
    const ushort* __restrict__ wtH, const ushort* __restrict__ wtL,
    const float* __restrict__ db, const float* __restrict__ bns,
    const float* __restrict__ bnb,
    ushort* __restrict__ oH, ushort* __restrict__ oL, int nOcg)
{
  constexpr int TR    = 64 / SW;
  constexpr int NRA   = TR + ((NPAR==4) ? 2 : 1);
  constexpr int WPin  = SW + 2;
  constexpr int AELEM = NRA * WPin * CIN;
  constexpr int OUTH  = 2*SH;
  constexpr int OW    = OUTPAD ? (2*SW+2) : (2*SW);

  __shared__ __align__(16) ushort sAh[AELEM], sAl[AELEM];

  int b = blockIdx.x;
  int p_blk = 0;
  if (NPAR == 2){ p_blk = b & 1; b >>= 1; }
  int ocg = b % nOcg; b /= nOcg;
  int tb = b % (SH/TR); b /= (SH/TR);
  int n = b;
  int t0 = tb * TR, oc0 = ocg * 64;
  const int ROWBASE = (NPAR==4) ? -1 : (p_blk - 1);

  int tid = threadIdx.x, l = tid&63, wave = tid>>6;
  int wm = wave>>1, wn = wave&1;
  int r = l&31, kp = l>>5;
  int idx = wm*32 + r;
  int t_off = idx / SW, s = idx % SW;
  int ocl = oc0 + wn*32 + r;

  float bn_s1 = bns[ocl];
  float bn_s2 = fmaf(db[ocl], bn_s1, bnb[ocl]);

  for (int c = tid; c < AELEM/8; c += 256){
    int j  = c / (WPin*CIN/8);
    int rm = c % (WPin*CIN/8);
    int lx = rm / (CIN/8);
    int c8 = (rm % (CIN/8)) * 8;
    int giy = t0 + ROWBASE + j;
    bool ok = (unsigned)giy < (unsigned)SH;
    short8 vh = {0,0,0,0,0,0,0,0}, vl = {0,0,0,0,0,0,0,0};
    if (ok){
      size_t sidx = (((size_t)n*SH + giy)*WPin + lx)*CIN + c8;
      vh = *(const short8*)(inH + sidx);
      vl = *(const short8*)(inL + sidx);
    }
    unsigned off = (unsigned)(((j*WPin + lx)*CIN + c8)*2) ^ (((unsigned)lx&15u)<<4);
    *(short8*)((char*)sAh + off) = vh;
    *(short8*)((char*)sAl + off) = vl;
  }
  __syncthreads();

  for (int pr = 0; pr < NPAR; pr++){
    int p2 = (NPAR==4) ? (pr>>1) : p_blk;
    int q2 = (NPAR==4) ? (pr&1)  : pr;
    int par = p2*2 + q2;

    f32x16 acc0, acc1, acc2;
    #pragma unroll
    for (int i=0;i<16;i++){ acc0[i]=0.f; acc1[i]=0.f; acc2[i]=0.f; }

    for (int ab = 0; ab < 4; ab++){
      int a = ab>>1, bb = ab&1;
      int rs = t_off + ((NPAR==4) ? (p2 + a) : a);
      int lx = s + q2 + bb;
      unsigned asw  = (((unsigned)lx&15u)<<4);
      unsigned alin = (unsigned)(((rs*WPin + lx)*CIN)*2);
      size_t brow = ((size_t)(par*4 + ab)*OC + ocl)*CIN;
      #pragma unroll
      for (int ct = 0; ct < CIN/16; ct++){
        int ko = ct*16 + kp*8;
        unsigned ao = (alin + (unsigned)(ko*2)) ^ asw;
        bf16x8 ah = *(const bf16x8*)((char*)sAh + ao);
        bf16x8 al = *(const bf16x8*)((char*)sAl + ao);
        bf16x8 bh = ldg8u(wtH + brow + ko);
        bf16x8 bl = ldg8u(wtL + brow + ko);
        acc0 = MFMA(ah, bh, acc0);
        acc1 = MFMA(ah, bl, acc1);
        acc2 = MFMA(al, bh, acc2);
      }
    }

    #pragma unroll
    for (int q = 0; q < 16; q++){
      int rowt = (q&3) + 8*(q>>2) + 4*kp;
      int m = wm*32 + rowt;
      int y  = 2*(t0 + m/SW) + p2;
      int xs = m % SW;
      int xp = OUTPAD ? (2*xs + q2 + 1) : (2*xs + q2);
      size_t base = (((size_t)n*OUTH + y)*OW + xp)*OC + ocl;
      float v = fmaxf(fmaf(acc0[q] + acc1[q] + acc2[q], bn_s1, bn_s2), 0.f);
      ushort h = f2bf(v);
      oH[base] = h;
      if constexpr (OMODE == 0){
        oL[base] = f2bf(v - bf2f(h));
      }
    }
  }
}

// ---------------------------------------------------------------------------
// convT4: 64->1ch + sigmoid + recon-loss. D3 single bf16 plane.
// ---------------------------------------------------------------------------
__global__ __launch_bounds__(256) void dec_convT4(
    const ushort* __restrict__ d3, const float* __restrict__ w4,
    const float* __restrict__ db4, const float* __restrict__ xref,
    float* __restrict__ recon, float* __restrict__ loss)
{
  __shared__ __align__(16) float sT[10*10*68];
  __shared__ __align__(16) float sWt[16*64];
  __shared__ float red[4];
  int b = blockIdx.x;
  int t = b & 255, n = b >> 8;
  int ty = t >> 4, tx = t & 15;
  int y0 = ty*16, x0 = tx*16;
  int r0 = y0/2 - 1, c0 = x0/2 - 1;
  int tid = threadIdx.x;

  *(float4*)&sWt[tid*4] = *(const float4*)(w4 + tid*4);

  const ushort* base = d3 + (size_t)n*128*128*64;
  for (int e = tid; e < 800; e += 256){
    int rr = e/80; int rem = e%80; int cc = rem/8; int c8 = (rem%8)*8;
    int gr = r0+rr, gc = c0+cc;
    short8 v = {0,0,0,0,0,0,0,0};
    if ((unsigned)gr<128u && (unsigned)gc<128u)
      v = *(const short8*)(base + ((size_t)gr*128+gc)*64 + c8);
    float* dst = &sT[(rr*10+cc)*68 + c8];
    float4 f0, f1;
    f0.x = bf2f((ushort)v[0]); f0.y = bf2f((ushort)v[1]);
    f0.z = bf2f((ushort)v[2]); f0.w = bf2f((ushort)v[3]);
    f1.x = bf2f((ushort)v[4]); f1.y = bf2f((ushort)v[5]);
    f1.z = bf2f((ushort)v[6]); f1.w = bf2f((ushort)v[7]);
    *(float4*)dst     = f0;
    *(float4*)(dst+4) = f1;
  }
  __syncthreads();

  int sy = tid>>4, sx = tid&15;
  int p = sy&1, q = sx&1;
  int lr0 = (sy>>1)+p, lc0 = (sx>>1)+q;
  int par = p*2+q;
  float4 a4 = {0,0,0,0};
  #pragma unroll
  for (int a=0;a<2;a++){
    #pragma unroll
    for (int bb=0;bb<2;bb++){
      const float* ip = &sT[((lr0+a)*10 + lc0+bb)*68];
      const float* wp = &sWt[(par*4+a*2+bb)*64];
      #pragma unroll
      for (int c=0;c<64;c+=4){
        float4 v  = *(const float4*)(ip+c);
        float4 wv = *(const float4*)(wp+c);
        a4.x = fmaf(v.x, wv.x, a4.x);
        a4.y = fmaf(v.y, wv.y, a4.y);
        a4.z = fmaf(v.z, wv.z, a4.z);
        a4.w = fmaf(v.w, wv.w, a4.w);
      }
    }
  }
  float acc = (a4.x + a4.y) + (a4.z + a4.w);
  float v = acc + db4[0];
  float rcn = 1.f/(1.f + __expf(-v));
  int y = y0+sy, x = x0+sx;
  size_t oi = (size_t)n*65536 + (size_t)y*256 + x;
  recon[oi] = rcn;
  float d = rcn - xref[oi];
  float s2 = wred64(d*d);
  if ((tid & 63)==0) red[tid>>6] = s2;
  __syncthreads();
  if (tid==0) atomicAdd(loss + 0, red[0]+red[1]+red[2]+red[3]);
}

// ---------------------------------------------------------------------------
__global__ __launch_bounds__(256) void k_final(
    const float* __restrict__ avgs, const unsigned int* __restrict__ cnt,
    const float* __restrict__ cluster, const float* __restrict__ loss,
    float* __restrict__ dout)
{
  __shared__ float red[3][4];
  int tid = threadIdx.x;
  float e1=0.f, e2=0.f, ac=0.f;
  for (int j=tid; j<8192; j+=256){
    float a = avgs[j] * (1.f/8192.f);
    e1 += a * __logf(a + 1e-10f);
    float h = (float)cnt[j] * (1.f/8192.f);
    e2 += h * __logf(h + 1e-10f);
    ac += (cluster[j] > 1.f) ? 1.f : 0.f;
  }
  e1 = wred64(e1); e2 = wred64(e2); ac = wred64(ac);
  int wv = tid >> 6;
  if ((tid & 63)==0){ red[0][wv]=e1; red[1][wv]=e2; red[2][wv]=ac; }
  __syncthreads();
  if (tid==0){
    float s1 = red[0][0]+red[0][1]+red[0][2]+red[0][3];
    float s2 = red[1][0]+red[1][1]+red[1][2]+red[1][3];
    float s3 = red[2][0]+red[2][1]+red[2][2]+red[2][3];
    float ue = -s1;
    dout[O_RLOSS]  = loss[0] * (1.f/2097152.f);
    float cc = loss[1] * (1.f/524288.f);
    dout[O_COMMIT] = cc;
    dout[O_CB]     = cc;
    dout[O_DIV]    = -ue / 9.010913347279288f;
    dout[O_UE]     = ue;
    dout[O_PERP]   = __expf(-s2);
    dout[O_ACT]    = s3;
  }
}

// ---------------------------------------------------------------------------
extern "C" void kernel_launch(void* const* d_in, const int* in_sizes, int n_in,
                              void* d_out, int out_size, void* d_ws, size_t ws_size,
                              hipStream_t stream)
{
  (void)in_sizes; (void)n_in; (void)out_size; (void)ws_size;
  const float* x     = (const float*)d_in[0];
  const float* ew1   = (const float*)d_in[1];
  const float* eb1   = (const float*)d_in[2];
  const float* bn1s  = (const float*)d_in[3];
  const float* bn1b  = (const float*)d_in[4];
  const float* ew2   = (const float*)d_in[5];
  const float* eb2   = (const float*)d_in[6];
  const float* bn2s  = (const float*)d_in[7];
  const float* bn2b  = (const float*)d_in[8];
  const float* ew3   = (const float*)d_in[9];
  const float* eb3   = (const float*)d_in[10];
  const float* bn3s  = (const float*)d_in[11];
  const float* bn3b  = (const float*)d_in[12];
  const float* ew4   = (const float*)d_in[13];
  const float* eb4   = (const float*)d_in[14];
  const float* embed = (const float*)d_in[15];
  const float* clsz  = (const float*)d_in[16];
  const float* dw1   = (const float*)d_in[17];
  const float* db1   = (const float*)d_in[18];
  const float* dbn1s = (const float*)d_in[19];
  const float* dbn1b = (const float*)d_in[20];
  const float* dw2   = (const float*)d_in[21];
  const float* db2   = (const float*)d_in[22];
  const float* dbn2s = (const float*)d_in[23];
  const float* dbn2b = (const float*)d_in[24];
  const float* dw3   = (const float*)d_in[25];
  const float* db3   = (const float*)d_in[26];
  const float* dbn3s = (const float*)d_in[27];
  const float* dbn3b = (const float*)d_in[28];
  const float* dw4   = (const float*)d_in[29];
  const float* db4   = (const float*)d_in[30];

  float* out = (float*)d_out;
  uint8_t* wsb = (uint8_t*)d_ws;

  float*  A1   = (float*)(wsb + WS_R1);
  ushort* D3b  = (ushort*)(wsb + WS_R1);
  ushort* A3h  = (ushort*)(wsb + A3H_OFF);
  ushort* A3m  = (ushort*)(wsb + A3M_OFF);
  ushort* A3l  = (ushort*)(wsb + A3L_OFF);
  float*  Pp   = (float*)(wsb + PP_OFF);
  float*  Mt   = (float*)(wsb + MT_OFF);
  float*  partA= (float*)(wsb + PARTA_OFF);
  ushort* A2h  = (ushort*)(wsb + A2H_OFF);
  ushort* A2m  = (ushort*)(wsb + A2M_OFF);
  ushort* A2l  = (ushort*)(wsb + A2L_OFF);
  ushort* eH   = (ushort*)(wsb + EH_OFF);
  ushort* eM   = (ushort*)(wsb + EM_OFF);
  ushort* eL   = (ushort*)(wsb + EL_OFF);
  ushort* fH   = (ushort*)(wsb + FH_OFF);
  ushort* fM   = (ushort*)(wsb + FM_OFF);
  ushort* fL   = (ushort*)(wsb + FL_OFF);
  ushort* D1h  = (ushort*)(wsb + D1H_OFF);
  ushort* D1l  = (ushort*)(wsb + D1L_OFF);
  ushort* D2h  = (ushort*)(wsb + D2H_OFF);
  ushort* D2l  = (ushort*)(wsb + D2L_OFF);
  float*  flat = (float*)(wsb + WS_FLAT);
  ushort* zqPh = (ushort*)(wsb + WS_ZQP);
  ushort* zqPl = (ushort*)(wsb + WS_ZQP + 1179648ull);

  ushort* wE2h = (ushort*)(wsb + WT_E2);
  ushort* wE2m = wE2h + 65536;  ushort* wE2l = wE2m + 65536;
  ushort* wE3h = (ushort*)(wsb + WT_E3);
  ushort* wE3m = wE3h + 131072; ushort* wE3l = wE3m + 131072;
  ushort* wE4h = (ushort*)(wsb + WT_E4);
  ushort* wE4m = wE4h + 131072; ushort* wE4l = wE4m + 131072;
  ushort* wD1h = (ushort*)(wsb + WT_D1);
  ushort* wD1l = wD1h + 131072;
  ushort* wD2h = (ushort*)(wsb + WT_D2);
  ushort* wD2l = wD2h + 131072;
  ushort* wD3h = (ushort*)(wsb + WT_D3);
  ushort* wD3l = wD3h + 65536;
  float*  w4   = (float*)(wsb + WS_W4);

  unsigned long long* rmp = (unsigned long long*)(wsb + ST_RMP);
  unsigned int* cnt = (unsigned int*)(wsb + ST_CNT);
  float* avgs   = (float*)(wsb + ST_AVGS);
  float* rowzi  = (float*)(wsb + ST_ROWZI);
  float* codesq = (float*)(wsb + ST_CODESQ);
  float* loss   = (float*)(wsb + ST_LOSS);
  float* rowm   = (float*)(wsb + ST_ROWM);

  dim3 B(256);

  k_prep<<<3236, B, 0, stream>>>(
      ew2, ew3, ew4, dw1, dw2, dw3, dw4,
      wE2h, wE2m, wE2l, wE3h, wE3m, wE3l, wE4h, wE4m, wE4l,
      wD1h, wD1l, wD2h, wD2l, wD3h, wD3l, w4,
      (unsigned*)A2h, (unsigned*)A2m, (unsigned*)A2l,
      (unsigned*)zqPh, (unsigned*)zqPl,
      cnt, rmp, loss);

  // encoder
  enc_conv1<<<2048, B, 0, stream>>>(x, ew1, eb1, bn1s, bn1b, A1);
  enc_conv<64,64,64,64,128,128,false,0,0><<<2048, B, 0, stream>>>(
      A1, nullptr, nullptr, nullptr, wE2h, wE2m, wE2l, eb2, bn2s, bn2b,
      nullptr, A2h, A2m, A2l, 1);
  k_zpadA3<<<512, B, 0, stream>>>((unsigned*)A3h, (unsigned*)A3m, (unsigned*)A3l);
  enc_conv<64,128,32,32,64,64,true,1,0><<<1024, B, 0, stream>>>(
      nullptr, A2h, A2m, A2l, wE3h, wE3m, wE3l, eb3, bn3s, bn3b,
      nullptr, A3h, A3m, A3l, 2);
  k_eprep<<<4096, B, 0, stream>>>(embed, eH, eM, eL, codesq);
  enc_conv<128,64,16,16,32,32,true,1,1><<<128, B, 0, stream>>>(
      nullptr, A3h, A3m, A3l, wE4h, wE4m, wE4l, eb4, eb4, eb4,
      flat, fH, fM, fL, 1);

  // VQ
  vq_min<<<4096, B, 0, stream>>>(fH, fM, fL, eH, eM, eL, codesq, rmp, Pp, Mt);
  k_rowz2<<<32, B, 0, stream>>>(rmp, Pp, Mt, rowzi, rowm);
  vq_avg<<<4096, B, 0, stream>>>(fH, fM, fL, eH, eM, eL, codesq, rowm, rowzi, partA);
  k_avgred<<<32, B, 0, stream>>>(partA, avgs);

  vq_post<<<3072, B, 0, stream>>>(flat, embed, rmp, out + O_CODES, out + O_ZQ,
                                  zqPh, zqPl, loss, cnt,
                                  (unsigned*)D1h, (unsigned*)D1l,
                                  (unsigned*)D2h, (unsigned*)D2l);

  // decoder (parity-merged, direct-store epilogue)
  dec_convT_m<64,128,16,16,true,0,4><<<256, B, 0, stream>>>(
      zqPh, zqPl, wD1h, wD1l, db1, dbn1s, dbn1b, D1h, D1l, 2);
  dec_convT_m<128,64,32,32,true,0,2><<<1024, B, 0, stream>>>(
      D1h, D1l, wD2h, wD2l, db2, dbn2s, dbn2b, D2h, D2l, 1);
  dec_convT_m<64,64,64,64,false,2,4><<<2048, B, 0, stream>>>(
      D2h, D2l, wD3h, wD3l, db3, dbn3s, dbn3b, D3b, nullptr, 1);
  dec_convT4<<<8192, B, 0, stream>>>(D3b, w4, db4, x, out + O_RECON, loss);

  k_final<<<1, B, 0, stream>>>(avgs, cnt, clsz, loss, out);
}